// Round 4
// baseline (3380.721 us; speedup 1.0000x reference)
//
#include <hip/hip_runtime.h>

typedef float f32x4 __attribute__((ext_vector_type(4)));
typedef __bf16 bf16x8 __attribute__((ext_vector_type(8)));

#define DI static __device__ __forceinline__

DI unsigned short f2bf(float f) {
  unsigned u = __float_as_uint(f);
  u = (u + 0x7fffu + ((u >> 16) & 1u)) >> 16;
  return (unsigned short)u;
}
DI unsigned pk2(float lo, float hi) {
  return (unsigned)f2bf(lo) | ((unsigned)f2bf(hi) << 16);
}
DI float bflo(unsigned u) { return __uint_as_float(u << 16); }
DI float bfhi(unsigned u) { return __uint_as_float(u & 0xffff0000u); }
DI float sigm(float x) { return 1.0f / (1.0f + expf(-x)); }

DI void gl_lds16(const unsigned short* g, unsigned short* l) {
  __builtin_amdgcn_global_load_lds(
      (const __attribute__((address_space(1))) unsigned int*)g,
      (__attribute__((address_space(3))) unsigned int*)l, 16, 0, 0);
}

// --- device-coherent (sc1) access helpers: data visible at L3 across XCDs ---
DI void st32_sc1(unsigned* p, unsigned v) {
  __hip_atomic_store(p, v, __ATOMIC_RELAXED, __HIP_MEMORY_SCOPE_AGENT);
}
DI void st64_sc1(unsigned long long* p, unsigned long long v) {
  __hip_atomic_store(p, v, __ATOMIC_RELAXED, __HIP_MEMORY_SCOPE_AGENT);
}
DI bf16x8 ld16_sc1(const unsigned short* p) {
  unsigned long long lo = __hip_atomic_load((const unsigned long long*)p,
                                            __ATOMIC_RELAXED, __HIP_MEMORY_SCOPE_AGENT);
  unsigned long long hi = __hip_atomic_load((const unsigned long long*)(p + 4),
                                            __ATOMIC_RELAXED, __HIP_MEMORY_SCOPE_AGENT);
  union { unsigned long long q[2]; bf16x8 v; } u;
  u.q[0] = lo; u.q[1] = hi;
  return u.v;
}

// Store-based grid barrier: block publishes arrival with ONE sc1 store to its
// own 16B-padded slot (no RMW serialization); wave 0 polls all slots in
// parallel (2 strided loads/lane + __all). Targets are monotonic per barrier;
// flags zeroed by the pre-kernel memset. Data ordering: __syncthreads drains
// vmcnt (sc1 stores at L3) before the flag store issues.
DI void gridbarf(int* flags, int nblk, int blk, int target) {
  __syncthreads();
  if (threadIdx.x < 64) {
    if (threadIdx.x == 0)
      __hip_atomic_store(&flags[blk << 2], target, __ATOMIC_RELAXED, __HIP_MEMORY_SCOPE_AGENT);
    const int i0 = (int)threadIdx.x * 2, i1 = i0 + 1;
    const bool n0 = i0 < nblk, n1 = i1 < nblk;
    for (;;) {
      int v0 = n0 ? __hip_atomic_load(&flags[i0 << 2], __ATOMIC_RELAXED, __HIP_MEMORY_SCOPE_AGENT) : target;
      int v1 = n1 ? __hip_atomic_load(&flags[i1 << 2], __ATOMIC_RELAXED, __HIP_MEMORY_SCOPE_AGENT) : target;
      if (__all(v0 >= target && v1 >= target)) break;
      __builtin_amdgcn_s_sleep(1);
    }
  }
  __syncthreads();
}

// ---------------------------------------------------------------------------
// Fold tiny per-feature projections + fi into M[1024][16], b0[1024]
// ---------------------------------------------------------------------------
__global__ void k_fold(const float* __restrict__ tW, const float* __restrict__ tb,
                       const float* __restrict__ hW, const float* __restrict__ hb,
                       const float* __restrict__ cW, const float* __restrict__ cb,
                       const float* __restrict__ tiW, const float* __restrict__ tib,
                       const float* __restrict__ oW, const float* __restrict__ ob,
                       const float* __restrict__ fiW, const float* __restrict__ fib,
                       float* __restrict__ M, float* __restrict__ b0v)
{
  int g = blockIdx.x * 256 + threadIdx.x;
  if (g >= 1024 * 17) return;
  int h = g / 17, f = g - h * 17;
  const float* fw = fiW + (size_t)h * 2048;
  float s = 0.f;
  if (f == 16) {
    for (int k = 0; k < 256; ++k) s += fw[k] * tb[k];
    for (int k = 0; k < 256; ++k) s += fw[256 + k] * hb[k];
    for (int k = 0; k < 256; ++k) s += fw[512 + k] * cb[k];
    for (int k = 0; k < 256; ++k) s += fw[768 + k] * tib[k];
    for (int r = 0; r < 1024; ++r) s += fw[1024 + r] * ob[r];
    b0v[h] = s + fib[h];
  } else if (f == 0) {
    for (int k = 0; k < 256; ++k) s += fw[k] * tW[k];
    M[h * 16 + 0] = s;
  } else if (f == 1) {
    for (int k = 0; k < 256; ++k) s += fw[256 + k] * hW[k];
    M[h * 16 + 1] = s;
  } else if (f == 2) {
    for (int k = 0; k < 256; ++k) s += fw[512 + k] * cW[k];
    M[h * 16 + 2] = s;
  } else if (f == 11) {
    for (int k = 0; k < 256; ++k) s += fw[768 + k] * tiW[2 * k];
    M[h * 16 + 11] = s;
  } else if (f == 12) {
    for (int k = 0; k < 256; ++k) s += fw[768 + k] * tiW[2 * k + 1];
    M[h * 16 + 12] = s;
  } else {
    int col = (f <= 10) ? (f - 3) : (f - 5);
    for (int r = 0; r < 1024; ++r) s += fw[1024 + r] * oW[r * 11 + col];
    M[h * 16 + f] = s;
  }
}

__global__ __launch_bounds__(256)
void k_proj(const float* __restrict__ feat, const float* __restrict__ M,
            const float* __restrict__ b0v, unsigned short* __restrict__ proj)
{
  __shared__ float ft[16];
  int bs = blockIdx.x;
  int h = blockIdx.y * 256 + threadIdx.x;
  if (threadIdx.x < 16) ft[threadIdx.x] = feat[bs * 16 + threadIdx.x];
  __syncthreads();
  float sum = b0v[h];
  const float* mr = M + h * 16;
#pragma unroll
  for (int f = 0; f < 16; ++f) sum += mr[f] * ft[f];
  proj[(size_t)bs * 1024 + h] = f2bf(tanhf(sum));
}

// ---------------------------------------------------------------------------
// fp32 -> bf16 converters
// ---------------------------------------------------------------------------
__global__ void k_conv(const float* __restrict__ s, unsigned short* __restrict__ d, int n8)
{
  for (long i = (long)blockIdx.x * 256 + threadIdx.x; i < n8; i += (long)gridDim.x * 256) {
    const float* p = s + i * 8;
    f32x4 a = *(const f32x4*)p, b = *(const f32x4*)(p + 4);
    uint4 o;
    o.x = pk2(a[0], a[1]); o.y = pk2(a[2], a[3]);
    o.z = pk2(b[0], b[1]); o.w = pk2(b[2], b[3]);
    *(uint4*)(d + i * 8) = o;
  }
}

// rows x 1024 from a ld-2048 matrix (col offset 0)
__global__ void k_conv_str(const float* __restrict__ s, unsigned short* __restrict__ d)
{
  int r = blockIdx.x;
  int c = threadIdx.x * 4;
  f32x4 a = *(const f32x4*)(s + (size_t)r * 2048 + c);
  uint2 o; o.x = pk2(a[0], a[1]); o.y = pk2(a[2], a[3]);
  *(uint2*)(d + (size_t)r * 1024 + c) = o;
}

__global__ void k_gather_e(const int* __restrict__ toks, const float* __restrict__ emb,
                           unsigned short* __restrict__ e_bf)
{
  int row = blockIdx.x;               // 2048
  int t = row >> 5, b = row & 31;
  unsigned short* dst = e_bf + (size_t)row * 1024 + threadIdx.x * 4;
  if (t < 63) {
    int tok = toks[b * 64 + t];
    f32x4 a = *(const f32x4*)(emb + (size_t)tok * 1024 + threadIdx.x * 4);
    uint2 o; o.x = pk2(a[0], a[1]); o.y = pk2(a[2], a[3]);
    *(uint2*)dst = o;
  } else {
    uint2 o; o.x = 0u; o.y = 0u;
    *(uint2*)dst = o;
  }
}

__global__ void k_onehot(const int* __restrict__ toks, float* __restrict__ out)
{
  int i = blockIdx.x * 256 + threadIdx.x;
  if (i >= 32 * 32000) return;
  int b = i / 32000, v = i - b * 32000;
  out[(size_t)b * 64 * 32000 + v] = (v == toks[0]) ? 1.0f : 0.0f;
}

// ---------------------------------------------------------------------------
// bf16 MFMA GEMM, m97 structure: C[M,N] = A[M,K] * B[N,K]^T + bias[N]
// ---------------------------------------------------------------------------
template<int MODE>
__global__ __launch_bounds__(256)
void gemm_bf(const unsigned short* __restrict__ A, const unsigned short* __restrict__ B,
             const float* __restrict__ bias, float* __restrict__ Cf,
             unsigned short* __restrict__ Cb,
             int tiles_m, int K, int lda, int ldb, int ldc, int coloff)
{
  __shared__ unsigned short As[4096];
  __shared__ unsigned short Bs[4096];
  const int nblk = gridDim.x;
  const int cpx = nblk >> 3;
  const int bid = blockIdx.x;
  const int id = (bid & 7) * cpx + (bid >> 3);     // XCD-contiguous work ids
  const int tm = id % tiles_m, tn = id / tiles_m;
  const int tid = threadIdx.x;
  const int lane = tid & 63, wave = tid >> 6;
  const int wm = (wave & 1) << 6, wn = (wave >> 1) << 6;
  const int r0 = tid >> 2, kc0 = (tid & 3) << 3;
  const unsigned short* ga0 = A + (size_t)(tm * 128 + r0) * lda + kc0;
  const unsigned short* ga1 = A + (size_t)(tm * 128 + 64 + r0) * lda + kc0;
  const unsigned short* gb0 = B + (size_t)(tn * 128 + r0) * ldb + kc0;
  const unsigned short* gb1 = B + (size_t)(tn * 128 + 64 + r0) * ldb + kc0;
  const int lr = lane & 15, lkb = (lane >> 4) << 3;

  f32x4 acc[4][4];
#pragma unroll
  for (int m = 0; m < 4; ++m)
#pragma unroll
    for (int n = 0; n < 4; ++n) { acc[m][n][0]=0.f; acc[m][n][1]=0.f; acc[m][n][2]=0.f; acc[m][n][3]=0.f; }

  for (int kt = 0; kt < K; kt += 32) {
    __syncthreads();
    gl_lds16(ga0 + kt, &As[tid * 8]);
    gl_lds16(ga1 + kt, &As[(tid + 256) * 8]);
    gl_lds16(gb0 + kt, &Bs[tid * 8]);
    gl_lds16(gb1 + kt, &Bs[(tid + 256) * 8]);
    __syncthreads();
    bf16x8 af[4], bfv[4];
#pragma unroll
    for (int m = 0; m < 4; ++m) af[m] = *(const bf16x8*)&As[(wm + m * 16 + lr) * 32 + lkb];
#pragma unroll
    for (int n = 0; n < 4; ++n) bfv[n] = *(const bf16x8*)&Bs[(wn + n * 16 + lr) * 32 + lkb];
#pragma unroll
    for (int m = 0; m < 4; ++m)
#pragma unroll
      for (int n = 0; n < 4; ++n)
        acc[m][n] = __builtin_amdgcn_mfma_f32_16x16x32_bf16(af[m], bfv[n], acc[m][n], 0, 0, 0);
  }

#pragma unroll
  for (int m = 0; m < 4; ++m) {
    int rb = tm * 128 + wm + m * 16 + ((lane >> 4) << 2);
#pragma unroll
    for (int n = 0; n < 4; ++n) {
      int c = tn * 128 + wn + n * 16 + lr;
      float bb = bias[c];
#pragma unroll
      for (int i = 0; i < 4; ++i) {
        float v = acc[m][n][i] + bb;
        int r = rb + i;
        if (MODE == 0) {
          Cf[(size_t)r * ldc + c] = v;
        } else if (MODE == 1) {
          Cb[(size_t)r * ldc + c] = f2bf(v);
        } else {
          if (r < 2016) {
            int t = r >> 5, b2 = r & 31;
            Cf[((size_t)b2 * 64 + t + 1) * 32000 + coloff + c] = v;
          }
        }
      }
    }
  }
}

// ---------------------------------------------------------------------------
// Persistent encoder scan. 64 blocks x 256. Cross-block h (bf16) via sc1
// stores/loads (hbf double-buffered -> addresses reused -> bypass L2).
// fp32 h state carried in registers per gate thread.
// ---------------------------------------------------------------------------
__global__ __launch_bounds__(256, 1)
void k_enc_scan(const float* __restrict__ gi_all, const float* __restrict__ whh,
                const float* __restrict__ bhh, unsigned short* __restrict__ hbf,
                float* __restrict__ hfp, unsigned short* __restrict__ enc_bf,
                int* __restrict__ flags)
{
  __shared__ unsigned short W[48 * 1024];
  __shared__ float Cred[4 * 2 * 3 * 64 * 4];
  const int tid = threadIdx.x;
  const int lane = tid & 63, wave = tid >> 6;
  const int j0 = blockIdx.x * 16;

  // stage 48 weight rows (r16,z16,n16) into LDS as bf16, XOR-swizzled chunks
  for (int i = tid; i < 48 * 128; i += 256) {
    int r = i >> 7, c = i & 127;
    int gr = ((r >> 4) << 10) + j0 + (r & 15);
    const float* src = whh + ((size_t)gr << 10) + (c << 3);
    f32x4 a = *(const f32x4*)src, b = *(const f32x4*)(src + 4);
    uint4 o;
    o.x = pk2(a[0], a[1]); o.y = pk2(a[2], a[3]);
    o.z = pk2(b[0], b[1]); o.w = pk2(b[2], b[3]);
    *(uint4*)&W[(r << 10) + ((c ^ (r & 7)) << 3)] = o;
  }
  __syncthreads();

  // per-thread gate cell decomposition (2 cells)
  int cb[2], cj[2], clb[2], creg[2], cm[2];
  float bh0[2], bh1[2], bh2[2];
  float hp[2] = {0.f, 0.f};          // fp32 h state lives in registers
#pragma unroll
  for (int cc = 0; cc < 2; ++cc) {
    int cell = tid + (cc << 8);
    cb[cc] = cell >> 4; cj[cc] = cell & 15;
    clb[cc] = ((cb[cc] & 15) >> 2) * 16;
    creg[cc] = cb[cc] & 3; cm[cc] = cb[cc] >> 4;
    bh0[cc] = bhh[j0 + cj[cc]];
    bh1[cc] = bhh[1024 + j0 + cj[cc]];
    bh2[cc] = bhh[2048 + j0 + cj[cc]];
  }

#pragma unroll 1
  for (int s = 0; s < 128; ++s) {
    const int rb = s & 1, wb = rb ^ 1;
    const unsigned short* hr = hbf + rb * 32768;

    // prefetch gi for gate phase (read-only, normal loads)
    float gp[2][3];
#pragma unroll
    for (int cc = 0; cc < 2; ++cc) {
      const float* gi = gi_all + ((size_t)cb[cc] * 128 + s) * 3072 + j0 + cj[cc];
      gp[cc][0] = gi[0]; gp[cc][1] = gi[1024]; gp[cc][2] = gi[2048];
    }

    // MFMA phase, wave handles k range [wave*256, wave*256+256)
    const int k0 = wave << 8;
    bf16x8 af[2][8];
#pragma unroll
    for (int kk = 0; kk < 8; ++kk) {
      int k = k0 + kk * 32 + ((lane >> 4) << 3);
      af[0][kk] = ld16_sc1(hr + (size_t)(lane & 15) * 1024 + k);
      af[1][kk] = ld16_sc1(hr + (size_t)(16 + (lane & 15)) * 1024 + k);
    }
    f32x4 acc[2][3];
#pragma unroll
    for (int m = 0; m < 2; ++m)
#pragma unroll
      for (int n = 0; n < 3; ++n) { acc[m][n][0]=0.f; acc[m][n][1]=0.f; acc[m][n][2]=0.f; acc[m][n][3]=0.f; }
#pragma unroll
    for (int kk = 0; kk < 8; ++kk) {
      int c = ((k0 + kk * 32) >> 3) + (lane >> 4);
#pragma unroll
      for (int n = 0; n < 3; ++n) {
        int wr = n * 16 + (lane & 15);
        bf16x8 bfr = *(const bf16x8*)&W[(wr << 10) + ((c ^ (wr & 7)) << 3)];
        acc[0][n] = __builtin_amdgcn_mfma_f32_16x16x32_bf16(af[0][kk], bfr, acc[0][n], 0, 0, 0);
        acc[1][n] = __builtin_amdgcn_mfma_f32_16x16x32_bf16(af[1][kk], bfr, acc[1][n], 0, 0, 0);
      }
    }
#pragma unroll
    for (int m = 0; m < 2; ++m)
#pragma unroll
      for (int n = 0; n < 3; ++n)
        *(f32x4*)&Cred[((((wave * 2 + m) * 3 + n) * 64) + lane) << 2] = acc[m][n];
    __syncthreads();

    // gate phase: 2 cells/thread
    float h2v[2];
#pragma unroll
    for (int cc = 0; cc < 2; ++cc) {
      int lj = clb[cc] + cj[cc], reg = creg[cc], m = cm[cc];
      float Cr = 0.f, Cz = 0.f, Cn = 0.f;
#pragma unroll
      for (int w = 0; w < 4; ++w) {
        Cr += Cred[((((w * 2 + m) * 3 + 0) * 64 + lj) << 2) + reg];
        Cz += Cred[((((w * 2 + m) * 3 + 1) * 64 + lj) << 2) + reg];
        Cn += Cred[((((w * 2 + m) * 3 + 2) * 64 + lj) << 2) + reg];
      }
      float r = sigm(gp[cc][0] + Cr + bh0[cc]);
      float z = sigm(gp[cc][1] + Cz + bh1[cc]);
      float n = tanhf(gp[cc][2] + r * (Cn + bh2[cc]));
      float h2 = (1.f - z) * n + z * hp[cc];
      h2v[cc] = h2; hp[cc] = h2;
    }
    // fp32 state export only at final step (consumed by decoder)
    if (s == 127) {
      hfp[cb[0] * 1024 + j0 + cj[0]] = h2v[0];
      hfp[cb[1] * 1024 + j0 + cj[1]] = h2v[1];
    }
    // packed bf16 writes: pair adjacent j via shfl, even lanes store 4B
    unsigned short s0 = f2bf(h2v[0]), s1 = f2bf(h2v[1]);
    unsigned o0 = (unsigned)__shfl_xor((int)(unsigned)s0, 1);
    unsigned o1 = (unsigned)__shfl_xor((int)(unsigned)s1, 1);
    if ((tid & 1) == 0) {
      int j = cj[0];                    // even
      unsigned p0 = (unsigned)s0 | (o0 << 16);
      unsigned p1 = (unsigned)s1 | (o1 << 16);
      st32_sc1((unsigned*)&hbf[wb * 32768 + cb[0] * 1024 + j0 + j], p0);
      st32_sc1((unsigned*)&hbf[wb * 32768 + cb[1] * 1024 + j0 + j], p1);
      *(unsigned*)&enc_bf[((size_t)cb[0] * 128 + s) * 1024 + j0 + j] = p0;
      *(unsigned*)&enc_bf[((size_t)cb[1] * 128 + s) * 1024 + j0 + j] = p1;
    }
    gridbarf(flags, 64, blockIdx.x, s + 1);
  }
}

// ---------------------------------------------------------------------------
// Persistent decoder scan. 128 blocks x 256. hcat rows are single-assignment:
// sc1 stores (publish to L3), normal first-touch loads are safe + L2-cacheable.
// fp32 h state in registers.
// ---------------------------------------------------------------------------
__global__ __launch_bounds__(256, 1)
void k_dec_scan(const float* __restrict__ gi_e, const float* __restrict__ whh,
                const float* __restrict__ wih, const float* __restrict__ bhh,
                const unsigned short* __restrict__ keys,
                const unsigned short* __restrict__ enc_bf,
                unsigned short* __restrict__ hcat, const float* __restrict__ hfp0,
                const unsigned short* __restrict__ hbf0, int* __restrict__ flags)
{
  __shared__ unsigned short Wh[32 * 1024];
  __shared__ unsigned short Wx[32 * 1024];
  __shared__ float Cred[4 * 2 * 2 * 64 * 4];
  __shared__ unsigned short hsh[1024];
  __shared__ float sarr[128];
  __shared__ float earr[128];
  const int tid = threadIdx.x;
  const int lane = tid & 63, wave = tid >> 6;
  const int blk = blockIdx.x;
  const int j0 = blk * 8;

  // stage weights: rows 0-7 r, 8-15 z, 16-23 n, 24-31 zero
  for (int i = tid; i < 32 * 128; i += 256) {
    int r = i >> 7, c = i & 127;
    int off = (r << 10) + ((c ^ (r & 7)) << 3);
    uint4 oh, ox;
    oh.x = oh.y = oh.z = oh.w = 0u; ox = oh;
    if (r < 24) {
      int gr = ((r >> 3) << 10) + j0 + (r & 7);
      const float* sh = whh + ((size_t)gr << 10) + (c << 3);
      f32x4 a = *(const f32x4*)sh, b = *(const f32x4*)(sh + 4);
      oh.x = pk2(a[0], a[1]); oh.y = pk2(a[2], a[3]);
      oh.z = pk2(b[0], b[1]); oh.w = pk2(b[2], b[3]);
      const float* sx = wih + ((size_t)gr << 11) + 1024 + (c << 3);
      f32x4 e = *(const f32x4*)sx, f = *(const f32x4*)(sx + 4);
      ox.x = pk2(e[0], e[1]); ox.y = pk2(e[2], e[3]);
      ox.z = pk2(f[0], f[1]); ox.w = pk2(f[2], f[3]);
    }
    *(uint4*)&Wh[off] = oh;
    *(uint4*)&Wx[off] = ox;
  }
  __syncthreads();

  // gate cell decomposition (1 cell/thread)
  const int gb = tid >> 3, gj = tid & 7;
  const int glb = ((gb & 15) >> 2) * 16;
  const int greg = gb & 3, gm = gb >> 4;
  const float bh0 = bhh[j0 + gj];
  const float bh1 = bhh[1024 + j0 + gj];
  const float bh2 = bhh[2048 + j0 + gj];
  float hpv = hfp0[gb * 1024 + j0 + gj];   // fp32 h state in register

#pragma unroll 1
  for (int t = 0; t < 63; ++t) {
    // ---------------- attention (blocks 0..31: one per batch) -------------
    if (blk < 32) {
      const int b = blk;
      const unsigned short* hsrc = (t == 0) ? (hbf0 + b * 1024)
                                            : (hcat + ((size_t)(t - 1) * 32 + b) * 2048);
      *(uint2*)&hsh[tid * 4] = *(const uint2*)(hsrc + tid * 4);
      __syncthreads();
      {
        int sp = tid >> 1, kh = (tid & 1) << 9;
        const unsigned short* kr = keys + ((size_t)b * 128 + sp) * 1024 + kh;
        float a = 0.f;
#pragma unroll 8
        for (int c = 0; c < 512; c += 8) {
          uint4 kv = *(const uint4*)(kr + c);
          uint4 hv = *(const uint4*)&hsh[kh + c];
          a += bflo(kv.x) * bflo(hv.x) + bfhi(kv.x) * bfhi(hv.x)
             + bflo(kv.y) * bflo(hv.y) + bfhi(kv.y) * bfhi(hv.y)
             + bflo(kv.z) * bflo(hv.z) + bfhi(kv.z) * bfhi(hv.z)
             + bflo(kv.w) * bflo(hv.w) + bfhi(kv.w) * bfhi(hv.w);
        }
        a += __shfl_xor(a, 1);
        if ((tid & 1) == 0) sarr[sp] = a * 0.03125f;
      }
      __syncthreads();
      float mx = -1e30f;
#pragma unroll 16
      for (int i2 = 0; i2 < 128; ++i2) mx = fmaxf(mx, sarr[i2]);
      if (tid < 128) earr[tid] = expf(sarr[tid] - mx);
      __syncthreads();
      float sum = 0.f;
#pragma unroll 16
      for (int i2 = 0; i2 < 128; ++i2) sum += earr[i2];
      float winv = 1.f / sum;
      f32x4 cacc; cacc[0]=0.f; cacc[1]=0.f; cacc[2]=0.f; cacc[3]=0.f;
      const unsigned short* eb = enc_bf + ((size_t)b << 17) + tid * 4;
#pragma unroll 4
      for (int s2 = 0; s2 < 128; ++s2) {
        float w = earr[s2] * winv;
        uint2 ev = *(const uint2*)(eb + ((size_t)s2 << 10));
        cacc[0] += w * bflo(ev.x); cacc[1] += w * bfhi(ev.x);
        cacc[2] += w * bflo(ev.y); cacc[3] += w * bfhi(ev.y);
      }
      unsigned long long cw = (unsigned long long)pk2(cacc[0], cacc[1])
                            | ((unsigned long long)pk2(cacc[2], cacc[3]) << 32);
      st64_sc1((unsigned long long*)(hcat + ((size_t)t * 32 + b) * 2048 + 1024 + tid * 4), cw);
    }
    gridbarf(flags, 128, blk, 2 * t + 1);

    // ---------------- GRU phase ------------------------------------------
    const float* gie = gi_e + ((size_t)t * 32 + gb) * 3072 + j0 + gj;
    float g0 = gie[0], g1 = gie[1024], g2 = gie[2048];

    const int part = wave >> 1;
    const int kh2 = (wave & 1) << 9;
    const unsigned short* abase;
    size_t astr;
    if (part == 0) {
      if (t == 0) { abase = hbf0; astr = 1024; }
      else { abase = hcat + (size_t)(t - 1) * 32 * 2048; astr = 2048; }
    } else {
      abase = hcat + (size_t)t * 32 * 2048 + 1024; astr = 2048;
    }
    const unsigned short* Wl = part ? Wx : Wh;
    f32x4 acc[2][2];
#pragma unroll
    for (int m = 0; m < 2; ++m)
#pragma unroll
      for (int n = 0; n < 2; ++n) { acc[m][n][0]=0.f; acc[m][n][1]=0.f; acc[m][n][2]=0.f; acc[m][n][3]=0.f; }
#pragma unroll
    for (int hh = 0; hh < 2; ++hh) {
      bf16x8 af[2][8];
#pragma unroll
      for (int kk = 0; kk < 8; ++kk) {
        int k = kh2 + hh * 256 + kk * 32 + ((lane >> 4) << 3);
        af[0][kk] = *(const bf16x8*)(abase + (size_t)(lane & 15) * astr + k);
        af[1][kk] = *(const bf16x8*)(abase + (size_t)(16 + (lane & 15)) * astr + k);
      }
#pragma unroll
      for (int kk = 0; kk < 8; ++kk) {
        int c = ((kh2 + hh * 256 + kk * 32) >> 3) + (lane >> 4);
#pragma unroll
        for (int n = 0; n < 2; ++n) {
          int wr = n * 16 + (lane & 15);
          bf16x8 bfr = *(const bf16x8*)&Wl[(wr << 10) + ((c ^ (wr & 7)) << 3)];
          acc[0][n] = __builtin_amdgcn_mfma_f32_16x16x32_bf16(af[0][kk], bfr, acc[0][n], 0, 0, 0);
          acc[1][n] = __builtin_amdgcn_mfma_f32_16x16x32_bf16(af[1][kk], bfr, acc[1][n], 0, 0, 0);
        }
      }
    }
#pragma unroll
    for (int m = 0; m < 2; ++m)
#pragma unroll
      for (int n = 0; n < 2; ++n)
        *(f32x4*)&Cred[((((wave * 2 + m) * 2 + n) * 64) + lane) << 2] = acc[m][n];
    __syncthreads();

    // gates: 1 cell/thread
    {
      float Chr = 0.f, Chz = 0.f, Chn = 0.f, Cxr = 0.f, Cxz = 0.f, Cxn = 0.f;
#pragma unroll
      for (int w = 0; w < 2; ++w) {
        Chr += Cred[((((w * 2 + gm) * 2 + 0) * 64 + glb + gj) << 2) + greg];
        Chz += Cred[((((w * 2 + gm) * 2 + 0) * 64 + glb + gj + 8) << 2) + greg];
        Chn += Cred[((((w * 2 + gm) * 2 + 1) * 64 + glb + gj) << 2) + greg];
        Cxr += Cred[(((((w + 2) * 2 + gm) * 2 + 0) * 64 + glb + gj) << 2) + greg];
        Cxz += Cred[(((((w + 2) * 2 + gm) * 2 + 0) * 64 + glb + gj + 8) << 2) + greg];
        Cxn += Cred[(((((w + 2) * 2 + gm) * 2 + 1) * 64 + glb + gj) << 2) + greg];
      }
      float r = sigm(g0 + Cxr + Chr + bh0);
      float z = sigm(g1 + Cxz + Chz + bh1);
      float n2 = tanhf(g2 + Cxn + r * (Chn + bh2));
      float h2 = (1.f - z) * n2 + z * hpv;
      hpv = h2;
      unsigned short sv = f2bf(h2);
      unsigned ov = (unsigned)__shfl_xor((int)(unsigned)sv, 1);
      if ((tid & 1) == 0) {
        unsigned pv = (unsigned)sv | (ov << 16);
        st32_sc1((unsigned*)&hcat[((size_t)t * 32 + gb) * 2048 + j0 + gj], pv);
      }
    }
    gridbarf(flags, 128, blk, 2 * t + 2);
  }
}

// ---------------------------------------------------------------------------
extern "C" void kernel_launch(void* const* d_in, const int* in_sizes, int n_in,
                              void* d_out, int out_size, void* d_ws, size_t ws_size,
                              hipStream_t stream)
{
  const float* features = (const float*)d_in[0];
  const int*   toks     = (const int*)d_in[1];
  const float* temp_W = (const float*)d_in[2];  const float* temp_b = (const float*)d_in[3];
  const float* hum_W  = (const float*)d_in[4];  const float* hum_b  = (const float*)d_in[5];
  const float* cloud_W= (const float*)d_in[6];  const float* cloud_b= (const float*)d_in[7];
  const float* time_W = (const float*)d_in[8];  const float* time_b = (const float*)d_in[9];
  const float* other_W= (const float*)d_in[10]; const float* other_b= (const float*)d_in[11];
  const float* fi_W   = (const float*)d_in[12]; const float* fi_b   = (const float*)d_in[13];
  const float* enc_wih= (const float*)d_in[14]; const float* enc_whh= (const float*)d_in[15];
  const float* enc_bih= (const float*)d_in[16]; const float* enc_bhh= (const float*)d_in[17];
  const float* emb    = (const float*)d_in[18];
  const float* attn_W = (const float*)d_in[19]; const float* attn_b = (const float*)d_in[20];
  const float* dec_wih= (const float*)d_in[21]; const float* dec_whh= (const float*)d_in[22];
  const float* dec_bih= (const float*)d_in[23]; const float* dec_bhh= (const float*)d_in[24];
  const float* out_W  = (const float*)d_in[25]; const float* out_b  = (const float*)d_in[26];
  float* out = (float*)d_out;
  char* ws = (char*)d_ws;

  int*            flagsE  = (int*)(ws + 0);                        // 1 KB (64*4 ints)
  int*            flagsD  = (int*)(ws + 1024);                     // 2 KB (128*4 ints)
  float*          Mf      = (float*)(ws + 4096);                   // 64 KB
  float*          b0v     = (float*)(ws + 69632);                  // 4 KB
  float*          hfp     = (float*)(ws + 73728);                  // 256 KB
  unsigned short* hbf     = (unsigned short*)(ws + 335872);        // 128 KB
  unsigned short* hcat    = (unsigned short*)(ws + 466944);        // 8 MB  [2048][2048]
  unsigned short* keys_bf = (unsigned short*)(ws + 8855552);       // 8 MB
  unsigned short* enc_bf  = (unsigned short*)(ws + 17244160);      // 8 MB
  float*          gi_e    = (float*)(ws + 25632768);               // 24 MB
  float*          gi_all  = (float*)(ws + 50798592);               // 48 MB
  unsigned short* proj_bf = (unsigned short*)(ws + 101130240);     // 8 MB
  unsigned short* e_bf    = (unsigned short*)(ws + 109518848);     // 4 MB
  unsigned short* wihE_bf = (unsigned short*)(ws + 113713152);     // 6 MB
  unsigned short* attnW_bf= (unsigned short*)(ws + 120004608);     // 2 MB
  unsigned short* wihD_bf = (unsigned short*)(ws + 122101760);     // 6 MB
  // out_W bf16 halves alias the (dead-by-then) gi_e/gi_all region
  unsigned short* outW_bf = (unsigned short*)(ws + 25632768);      // 62.5 MB

  // zero barrier flags, h state, hcat padding rows (2016..2047)
  hipMemsetAsync(ws, 0, 4096, stream);
  hipMemsetAsync(ws + 73728, 0, 262144 + 131072, stream);
  hipMemsetAsync(ws + 466944 + (size_t)2016 * 2048 * 2, 0, 32 * 2048 * 2, stream);

  // weight conversions
  k_conv<<<1536, 256, 0, stream>>>(enc_wih, wihE_bf, 393216);
  k_conv<<<512, 256, 0, stream>>>(attn_W, attnW_bf, 131072);
  k_conv_str<<<3072, 256, 0, stream>>>(dec_wih, wihD_bf);

  // feature pipeline
  k_fold<<<68, 256, 0, stream>>>(temp_W, temp_b, hum_W, hum_b, cloud_W, cloud_b,
                                 time_W, time_b, other_W, other_b, fi_W, fi_b, Mf, b0v);
  k_proj<<<dim3(4096, 4), 256, 0, stream>>>(features, Mf, b0v, proj_bf);

  // encoder input gates (batched): gi_all[4096,3072]
  gemm_bf<0><<<768, 256, 0, stream>>>(proj_bf, wihE_bf, enc_bih, gi_all, nullptr,
                                      32, 1024, 1024, 1024, 3072, 0);
  // encoder scan (persistent)
  k_enc_scan<<<64, 256, 0, stream>>>(gi_all, enc_whh, enc_bhh, hbf, hfp, enc_bf, flagsE);

  // attention keys (bf16 out)
  gemm_bf<1><<<256, 256, 0, stream>>>(enc_bf, attnW_bf, attn_b, nullptr, keys_bf,
                                      32, 1024, 1024, 1024, 1024, 0);
  // decoder embedding-path gates
  k_gather_e<<<2048, 256, 0, stream>>>(toks, emb, e_bf);
  gemm_bf<0><<<384, 256, 0, stream>>>(e_bf, wihD_bf, dec_bih, gi_e, nullptr,
                                      16, 1024, 1024, 1024, 3072, 0);
  // decoder scan (persistent)
  k_dec_scan<<<128, 256, 0, stream>>>(gi_e, dec_whh, dec_wih, dec_bhh, keys_bf,
                                      enc_bf, hcat, hfp, hbf, flagsD);

  // batched output projection in two N-halves (outW_bf aliases dead buffers)
  k_conv<<<2048, 256, 0, stream>>>(out_W, outW_bf, 4096000);
  gemm_bf<2><<<2000, 256, 0, stream>>>(hcat, outW_bf, out_b, out, nullptr,
                                       16, 2048, 2048, 2048, 0, 0);
  k_conv<<<2048, 256, 0, stream>>>(out_W + (size_t)16000 * 2048, outW_bf, 4096000);
  gemm_bf<2><<<2000, 256, 0, stream>>>(hcat, outW_bf, out_b + 16000, out, nullptr,
                                       16, 2048, 2048, 2048, 0, 16000);
  // out[:, 0, :] one-hot
  k_onehot<<<4000, 256, 0, stream>>>(toks, out);
}

// Round 5
// 2974.443 us; speedup vs baseline: 1.1366x; 1.1366x over previous
//
#include <hip/hip_runtime.h>

typedef float f32x4 __attribute__((ext_vector_type(4)));
typedef __bf16 bf16x8 __attribute__((ext_vector_type(8)));

#define DI static __device__ __forceinline__

DI unsigned short f2bf(float f) {
  unsigned u = __float_as_uint(f);
  u = (u + 0x7fffu + ((u >> 16) & 1u)) >> 16;
  return (unsigned short)u;
}
DI unsigned pk2(float lo, float hi) {
  return (unsigned)f2bf(lo) | ((unsigned)f2bf(hi) << 16);
}
DI float bflo(unsigned u) { return __uint_as_float(u << 16); }
DI float bfhi(unsigned u) { return __uint_as_float(u & 0xffff0000u); }
DI float sigm(float x) { return 1.0f / (1.0f + expf(-x)); }

DI void gl_lds16(const unsigned short* g, unsigned short* l) {
  __builtin_amdgcn_global_load_lds(
      (const __attribute__((address_space(1))) unsigned int*)g,
      (__attribute__((address_space(3))) unsigned int*)l, 16, 0, 0);
}

DI void st32_sc1(unsigned* p, unsigned v) {
  __hip_atomic_store(p, v, __ATOMIC_RELAXED, __HIP_MEMORY_SCOPE_AGENT);
}
DI void st64_sc1(unsigned long long* p, unsigned long long v) {
  __hip_atomic_store(p, v, __ATOMIC_RELAXED, __HIP_MEMORY_SCOPE_AGENT);
}
DI int ldw(const int* p) {
  return __hip_atomic_load(p, __ATOMIC_RELAXED, __HIP_MEMORY_SCOPE_AGENT);
}
DI void stw(int* p, int v) {
  __hip_atomic_store(p, v, __ATOMIC_RELAXED, __HIP_MEMORY_SCOPE_AGENT);
}
// Wait on a single release word (all lanes poll uniformly; compiler membar
// keeps later loads from hoisting above the spin).
DI void waitword(const int* w, int gen) {
  while (ldw(w) < gen) __builtin_amdgcn_s_sleep(1);
  asm volatile("" ::: "memory");
}

// ---------------------------------------------------------------------------
// Fold tiny per-feature projections + fi into M[1024][16], b0[1024]
// ---------------------------------------------------------------------------
__global__ void k_fold(const float* __restrict__ tW, const float* __restrict__ tb,
                       const float* __restrict__ hW, const float* __restrict__ hb,
                       const float* __restrict__ cW, const float* __restrict__ cb,
                       const float* __restrict__ tiW, const float* __restrict__ tib,
                       const float* __restrict__ oW, const float* __restrict__ ob,
                       const float* __restrict__ fiW, const float* __restrict__ fib,
                       float* __restrict__ M, float* __restrict__ b0v)
{
  int g = blockIdx.x * 256 + threadIdx.x;
  if (g >= 1024 * 17) return;
  int h = g / 17, f = g - h * 17;
  const float* fw = fiW + (size_t)h * 2048;
  float s = 0.f;
  if (f == 16) {
    for (int k = 0; k < 256; ++k) s += fw[k] * tb[k];
    for (int k = 0; k < 256; ++k) s += fw[256 + k] * hb[k];
    for (int k = 0; k < 256; ++k) s += fw[512 + k] * cb[k];
    for (int k = 0; k < 256; ++k) s += fw[768 + k] * tib[k];
    for (int r = 0; r < 1024; ++r) s += fw[1024 + r] * ob[r];
    b0v[h] = s + fib[h];
  } else if (f == 0) {
    for (int k = 0; k < 256; ++k) s += fw[k] * tW[k];
    M[h * 16 + 0] = s;
  } else if (f == 1) {
    for (int k = 0; k < 256; ++k) s += fw[256 + k] * hW[k];
    M[h * 16 + 1] = s;
  } else if (f == 2) {
    for (int k = 0; k < 256; ++k) s += fw[512 + k] * cW[k];
    M[h * 16 + 2] = s;
  } else if (f == 11) {
    for (int k = 0; k < 256; ++k) s += fw[768 + k] * tiW[2 * k];
    M[h * 16 + 11] = s;
  } else if (f == 12) {
    for (int k = 0; k < 256; ++k) s += fw[768 + k] * tiW[2 * k + 1];
    M[h * 16 + 12] = s;
  } else {
    int col = (f <= 10) ? (f - 3) : (f - 5);
    for (int r = 0; r < 1024; ++r) s += fw[1024 + r] * oW[r * 11 + col];
    M[h * 16 + f] = s;
  }
}

__global__ __launch_bounds__(256)
void k_proj(const float* __restrict__ feat, const float* __restrict__ M,
            const float* __restrict__ b0v, unsigned short* __restrict__ proj)
{
  __shared__ float ft[16];
  int bs = blockIdx.x;
  int h = blockIdx.y * 256 + threadIdx.x;
  if (threadIdx.x < 16) ft[threadIdx.x] = feat[bs * 16 + threadIdx.x];
  __syncthreads();
  float sum = b0v[h];
  const float* mr = M + h * 16;
#pragma unroll
  for (int f = 0; f < 16; ++f) sum += mr[f] * ft[f];
  proj[(size_t)bs * 1024 + h] = f2bf(tanhf(sum));
}

// ---------------------------------------------------------------------------
// fp32 -> bf16 converters
// ---------------------------------------------------------------------------
__global__ void k_conv(const float* __restrict__ s, unsigned short* __restrict__ d, int n8)
{
  for (long i = (long)blockIdx.x * 256 + threadIdx.x; i < n8; i += (long)gridDim.x * 256) {
    const float* p = s + i * 8;
    f32x4 a = *(const f32x4*)p, b = *(const f32x4*)(p + 4);
    uint4 o;
    o.x = pk2(a[0], a[1]); o.y = pk2(a[2], a[3]);
    o.z = pk2(b[0], b[1]); o.w = pk2(b[2], b[3]);
    *(uint4*)(d + i * 8) = o;
  }
}

__global__ void k_conv_str(const float* __restrict__ s, unsigned short* __restrict__ d)
{
  int r = blockIdx.x;
  int c = threadIdx.x * 4;
  f32x4 a = *(const f32x4*)(s + (size_t)r * 2048 + c);
  uint2 o; o.x = pk2(a[0], a[1]); o.y = pk2(a[2], a[3]);
  *(uint2*)(d + (size_t)r * 1024 + c) = o;
}

__global__ void k_gather_e(const int* __restrict__ toks, const float* __restrict__ emb,
                           unsigned short* __restrict__ e_bf)
{
  int row = blockIdx.x;               // 2048
  int t = row >> 5, b = row & 31;
  unsigned short* dst = e_bf + (size_t)row * 1024 + threadIdx.x * 4;
  if (t < 63) {
    int tok = toks[b * 64 + t];
    f32x4 a = *(const f32x4*)(emb + (size_t)tok * 1024 + threadIdx.x * 4);
    uint2 o; o.x = pk2(a[0], a[1]); o.y = pk2(a[2], a[3]);
    *(uint2*)dst = o;
  } else {
    uint2 o; o.x = 0u; o.y = 0u;
    *(uint2*)dst = o;
  }
}

__global__ void k_onehot(const int* __restrict__ toks, float* __restrict__ out)
{
  int i = blockIdx.x * 256 + threadIdx.x;
  if (i >= 32 * 32000) return;
  int b = i / 32000, v = i - b * 32000;
  out[(size_t)b * 64 * 32000 + v] = (v == toks[0]) ? 1.0f : 0.0f;
}

// ---------------------------------------------------------------------------
// bf16 MFMA GEMM, m97 structure: C[M,N] = A[M,K] * B[N,K]^T + bias[N]
// ---------------------------------------------------------------------------
template<int MODE>
__global__ __launch_bounds__(256)
void gemm_bf(const unsigned short* __restrict__ A, const unsigned short* __restrict__ B,
             const float* __restrict__ bias, float* __restrict__ Cf,
             unsigned short* __restrict__ Cb,
             int tiles_m, int K, int lda, int ldb, int ldc, int coloff)
{
  __shared__ unsigned short As[4096];
  __shared__ unsigned short Bs[4096];
  const int nblk = gridDim.x;
  const int cpx = nblk >> 3;
  const int bid = blockIdx.x;
  const int id = (bid & 7) * cpx + (bid >> 3);     // XCD-contiguous work ids
  const int tm = id % tiles_m, tn = id / tiles_m;
  const int tid = threadIdx.x;
  const int lane = tid & 63, wave = tid >> 6;
  const int wm = (wave & 1) << 6, wn = (wave >> 1) << 6;
  const int r0 = tid >> 2, kc0 = (tid & 3) << 3;
  const unsigned short* ga0 = A + (size_t)(tm * 128 + r0) * lda + kc0;
  const unsigned short* ga1 = A + (size_t)(tm * 128 + 64 + r0) * lda + kc0;
  const unsigned short* gb0 = B + (size_t)(tn * 128 + r0) * ldb + kc0;
  const unsigned short* gb1 = B + (size_t)(tn * 128 + 64 + r0) * ldb + kc0;
  const int lr = lane & 15, lkb = (lane >> 4) << 3;

  f32x4 acc[4][4];
#pragma unroll
  for (int m = 0; m < 4; ++m)
#pragma unroll
    for (int n = 0; n < 4; ++n) { acc[m][n][0]=0.f; acc[m][n][1]=0.f; acc[m][n][2]=0.f; acc[m][n][3]=0.f; }

  for (int kt = 0; kt < K; kt += 32) {
    __syncthreads();
    gl_lds16(ga0 + kt, &As[tid * 8]);
    gl_lds16(ga1 + kt, &As[(tid + 256) * 8]);
    gl_lds16(gb0 + kt, &Bs[tid * 8]);
    gl_lds16(gb1 + kt, &Bs[(tid + 256) * 8]);
    __syncthreads();
    bf16x8 af[4], bfv[4];
#pragma unroll
    for (int m = 0; m < 4; ++m) af[m] = *(const bf16x8*)&As[(wm + m * 16 + lr) * 32 + lkb];
#pragma unroll
    for (int n = 0; n < 4; ++n) bfv[n] = *(const bf16x8*)&Bs[(wn + n * 16 + lr) * 32 + lkb];
#pragma unroll
    for (int m = 0; m < 4; ++m)
#pragma unroll
      for (int n = 0; n < 4; ++n)
        acc[m][n] = __builtin_amdgcn_mfma_f32_16x16x32_bf16(af[m], bfv[n], acc[m][n], 0, 0, 0);
  }

#pragma unroll
  for (int m = 0; m < 4; ++m) {
    int rb = tm * 128 + wm + m * 16 + ((lane >> 4) << 2);
#pragma unroll
    for (int n = 0; n < 4; ++n) {
      int c = tn * 128 + wn + n * 16 + lr;
      float bb = bias[c];
#pragma unroll
      for (int i = 0; i < 4; ++i) {
        float v = acc[m][n][i] + bb;
        int r = rb + i;
        if (MODE == 0) {
          Cf[(size_t)r * ldc + c] = v;
        } else if (MODE == 1) {
          Cb[(size_t)r * ldc + c] = f2bf(v);
        } else {
          if (r < 2016) {
            int t = r >> 5, b2 = r & 31;
            Cf[((size_t)b2 * 64 + t + 1) * 32000 + coloff + c] = v;
          }
        }
      }
    }
  }
}

// ---------------------------------------------------------------------------
// Persistent encoder scan. 64 worker blocks + 1 master block.
// h history lives directly in enc_bf[b][s][j] (single-assignment rows):
// sc1-publish, normal-load. h(-1)=0 -> skip MFMA at s=0.
// ---------------------------------------------------------------------------
__global__ __launch_bounds__(256, 1)
void k_enc_scan(const float* __restrict__ gi_all, const float* __restrict__ whh,
                const float* __restrict__ bhh, float* __restrict__ hfp,
                unsigned short* __restrict__ enc_bf,
                int* __restrict__ arrE, int* __restrict__ relE)
{
  const int tid = threadIdx.x;
  const int blk = blockIdx.x;
  if (blk == 64) {                         // master: sweep + single-word release
    if (tid < 64) {
      for (int g = 1; g <= 128; ++g) {
        for (;;) {
          int v = ldw(&arrE[tid << 2]);
          if (__all(v >= g)) break;
          __builtin_amdgcn_s_sleep(1);
        }
        asm volatile("" ::: "memory");
        if (tid == 0) stw(relE, g);
      }
    }
    return;
  }

  __shared__ unsigned short W[48 * 1024];
  __shared__ float Cred[4 * 2 * 3 * 64 * 4];
  const int lane = tid & 63, wave = tid >> 6;
  const int j0 = blk * 16;

  for (int i = tid; i < 48 * 128; i += 256) {
    int r = i >> 7, c = i & 127;
    int gr = ((r >> 4) << 10) + j0 + (r & 15);
    const float* src = whh + ((size_t)gr << 10) + (c << 3);
    f32x4 a = *(const f32x4*)src, b = *(const f32x4*)(src + 4);
    uint4 o;
    o.x = pk2(a[0], a[1]); o.y = pk2(a[2], a[3]);
    o.z = pk2(b[0], b[1]); o.w = pk2(b[2], b[3]);
    *(uint4*)&W[(r << 10) + ((c ^ (r & 7)) << 3)] = o;
  }
  __syncthreads();

  int cb[2], cj[2], clb[2], creg[2], cm[2];
  float bh0[2], bh1[2], bh2[2];
  float hp[2] = {0.f, 0.f};
#pragma unroll
  for (int cc = 0; cc < 2; ++cc) {
    int cell = tid + (cc << 8);
    cb[cc] = cell >> 4; cj[cc] = cell & 15;
    clb[cc] = ((cb[cc] & 15) >> 2) * 16;
    creg[cc] = cb[cc] & 3; cm[cc] = cb[cc] >> 4;
    bh0[cc] = bhh[j0 + cj[cc]];
    bh1[cc] = bhh[1024 + j0 + cj[cc]];
    bh2[cc] = bhh[2048 + j0 + cj[cc]];
  }

#pragma unroll 1
  for (int s = 0; s < 128; ++s) {
    // prefetch gi (independent of waits)
    float gp[2][3];
#pragma unroll
    for (int cc = 0; cc < 2; ++cc) {
      const float* gi = gi_all + ((size_t)cb[cc] * 128 + s) * 3072 + j0 + cj[cc];
      gp[cc][0] = gi[0]; gp[cc][1] = gi[1024]; gp[cc][2] = gi[2048];
    }

    f32x4 acc[2][3];
#pragma unroll
    for (int m = 0; m < 2; ++m)
#pragma unroll
      for (int n = 0; n < 3; ++n) { acc[m][n][0]=0.f; acc[m][n][1]=0.f; acc[m][n][2]=0.f; acc[m][n][3]=0.f; }

    if (s > 0) {
      waitword(relE, s);                   // h(s-1) published
      const unsigned short* hr = enc_bf + (size_t)(s - 1) * 1024;   // + b*131072
      const int k0 = wave << 8;
      bf16x8 af[2][8];
#pragma unroll
      for (int kk = 0; kk < 8; ++kk) {
        int k = k0 + kk * 32 + ((lane >> 4) << 3);
        af[0][kk] = *(const bf16x8*)(hr + (size_t)(lane & 15) * 131072 + k);
        af[1][kk] = *(const bf16x8*)(hr + (size_t)(16 + (lane & 15)) * 131072 + k);
      }
#pragma unroll
      for (int kk = 0; kk < 8; ++kk) {
        int c = ((k0 + kk * 32) >> 3) + (lane >> 4);
#pragma unroll
        for (int n = 0; n < 3; ++n) {
          int wr = n * 16 + (lane & 15);
          bf16x8 bfr = *(const bf16x8*)&W[(wr << 10) + ((c ^ (wr & 7)) << 3)];
          acc[0][n] = __builtin_amdgcn_mfma_f32_16x16x32_bf16(af[0][kk], bfr, acc[0][n], 0, 0, 0);
          acc[1][n] = __builtin_amdgcn_mfma_f32_16x16x32_bf16(af[1][kk], bfr, acc[1][n], 0, 0, 0);
        }
      }
    }
#pragma unroll
    for (int m = 0; m < 2; ++m)
#pragma unroll
      for (int n = 0; n < 3; ++n)
        *(f32x4*)&Cred[((((wave * 2 + m) * 3 + n) * 64) + lane) << 2] = acc[m][n];
    __syncthreads();

    float h2v[2];
#pragma unroll
    for (int cc = 0; cc < 2; ++cc) {
      int lj = clb[cc] + cj[cc], reg = creg[cc], m = cm[cc];
      float Cr = 0.f, Cz = 0.f, Cn = 0.f;
#pragma unroll
      for (int w = 0; w < 4; ++w) {
        Cr += Cred[((((w * 2 + m) * 3 + 0) * 64 + lj) << 2) + reg];
        Cz += Cred[((((w * 2 + m) * 3 + 1) * 64 + lj) << 2) + reg];
        Cn += Cred[((((w * 2 + m) * 3 + 2) * 64 + lj) << 2) + reg];
      }
      float r = sigm(gp[cc][0] + Cr + bh0[cc]);
      float z = sigm(gp[cc][1] + Cz + bh1[cc]);
      float n = tanhf(gp[cc][2] + r * (Cn + bh2[cc]));
      float h2 = (1.f - z) * n + z * hp[cc];
      h2v[cc] = h2; hp[cc] = h2;
    }
    if (s == 127) {
      hfp[cb[0] * 1024 + j0 + cj[0]] = h2v[0];
      hfp[cb[1] * 1024 + j0 + cj[1]] = h2v[1];
    }
    unsigned short s0 = f2bf(h2v[0]), s1 = f2bf(h2v[1]);
    unsigned o0 = (unsigned)__shfl_xor((int)(unsigned)s0, 1);
    unsigned o1 = (unsigned)__shfl_xor((int)(unsigned)s1, 1);
    if ((tid & 1) == 0) {
      int j = cj[0];                       // even
      st32_sc1((unsigned*)&enc_bf[((size_t)cb[0] * 128 + s) * 1024 + j0 + j],
               (unsigned)s0 | (o0 << 16));
      st32_sc1((unsigned*)&enc_bf[((size_t)cb[1] * 128 + s) * 1024 + j0 + j],
               (unsigned)s1 | (o1 << 16));
    }
    __syncthreads();                       // drain stores before arrival
    if (tid == 0) stw(&arrE[blk << 2], s + 1);
  }
}

// ---------------------------------------------------------------------------
// Persistent decoder scan. 128 worker blocks + 1 master. Overlap: waves 0-1
// start Wh*h right after h-release; waves 2-3 wait only for ctx-release.
// ---------------------------------------------------------------------------
__global__ __launch_bounds__(256, 1)
void k_dec_scan(const float* __restrict__ gi_e, const float* __restrict__ whh,
                const float* __restrict__ wih, const float* __restrict__ bhh,
                const unsigned short* __restrict__ keys,
                const unsigned short* __restrict__ enc_bf,
                unsigned short* __restrict__ hcat, const float* __restrict__ hfp0,
                int* __restrict__ arrC, int* __restrict__ relC,
                int* __restrict__ arrH, int* __restrict__ relH)
{
  const int tid = threadIdx.x;
  const int blk = blockIdx.x;
  if (blk == 128) {                        // master
    if (tid < 64) {
      for (int g = 1; g <= 63; ++g) {
        for (;;) {
          int v = (tid < 32) ? ldw(&arrC[tid << 2]) : g;
          if (__all(v >= g)) break;
          __builtin_amdgcn_s_sleep(1);
        }
        asm volatile("" ::: "memory");
        if (tid == 0) stw(relC, g);
        for (;;) {
          int v0 = ldw(&arrH[(tid * 2) << 2]);
          int v1 = ldw(&arrH[(tid * 2 + 1) << 2]);
          if (__all(v0 >= g && v1 >= g)) break;
          __builtin_amdgcn_s_sleep(1);
        }
        asm volatile("" ::: "memory");
        if (tid == 0) stw(relH, g);
      }
    }
    return;
  }

  __shared__ unsigned short Wh[32 * 1024];
  __shared__ unsigned short Wx[32 * 1024];
  __shared__ float Cred[4 * 2 * 2 * 64 * 4];
  __shared__ unsigned short hsh[1024];
  __shared__ float sarr[128];
  __shared__ float earr[128];
  const int lane = tid & 63, wave = tid >> 6;
  const int j0 = blk * 8;

  for (int i = tid; i < 32 * 128; i += 256) {
    int r = i >> 7, c = i & 127;
    int off = (r << 10) + ((c ^ (r & 7)) << 3);
    uint4 oh, ox;
    oh.x = oh.y = oh.z = oh.w = 0u; ox = oh;
    if (r < 24) {
      int gr = ((r >> 3) << 10) + j0 + (r & 7);
      const float* sh = whh + ((size_t)gr << 10) + (c << 3);
      f32x4 a = *(const f32x4*)sh, b = *(const f32x4*)(sh + 4);
      oh.x = pk2(a[0], a[1]); oh.y = pk2(a[2], a[3]);
      oh.z = pk2(b[0], b[1]); oh.w = pk2(b[2], b[3]);
      const float* sx = wih + ((size_t)gr << 11) + 1024 + (c << 3);
      f32x4 e = *(const f32x4*)sx, f = *(const f32x4*)(sx + 4);
      ox.x = pk2(e[0], e[1]); ox.y = pk2(e[2], e[3]);
      ox.z = pk2(f[0], f[1]); ox.w = pk2(f[2], f[3]);
    }
    *(uint4*)&Wh[off] = oh;
    *(uint4*)&Wx[off] = ox;
  }
  __syncthreads();

  const int gb = tid >> 3, gj = tid & 7;
  const int glb = ((gb & 15) >> 2) * 16;
  const int greg = gb & 3, gm = gb >> 4;
  const float bh0 = bhh[j0 + gj];
  const float bh1 = bhh[1024 + j0 + gj];
  const float bh2 = bhh[2048 + j0 + gj];
  float hpv = hfp0[gb * 1024 + j0 + gj];

#pragma unroll 1
  for (int t = 0; t < 63; ++t) {
    const int gen = t + 1;
    // prefetch gi (independent of waits)
    const float* gie = gi_e + ((size_t)t * 32 + gb) * 3072 + j0 + gj;
    float g0 = gie[0], g1 = gie[1024], g2 = gie[2048];

    // ---------------- attention (blocks 0..31) ----------------------------
    if (blk < 32) {
      if (t) waitword(relH, t);
      const int b = blk;
      const unsigned short* hsrc = (t == 0)
          ? (enc_bf + (size_t)b * 131072 + (size_t)127 * 1024)
          : (hcat + ((size_t)(t - 1) * 32 + b) * 2048);
      *(uint2*)&hsh[tid * 4] = *(const uint2*)(hsrc + tid * 4);
      __syncthreads();
      {
        int sp = tid >> 1, kh = (tid & 1) << 9;
        const unsigned short* kr = keys + ((size_t)b * 128 + sp) * 1024 + kh;
        float a = 0.f;
#pragma unroll 8
        for (int c = 0; c < 512; c += 8) {
          uint4 kv = *(const uint4*)(kr + c);
          uint4 hv = *(const uint4*)&hsh[kh + c];
          a += bflo(kv.x) * bflo(hv.x) + bfhi(kv.x) * bfhi(hv.x)
             + bflo(kv.y) * bflo(hv.y) + bfhi(kv.y) * bfhi(hv.y)
             + bflo(kv.z) * bflo(hv.z) + bfhi(kv.z) * bfhi(hv.z)
             + bflo(kv.w) * bflo(hv.w) + bfhi(kv.w) * bfhi(hv.w);
        }
        a += __shfl_xor(a, 1);
        if ((tid & 1) == 0) sarr[sp] = a * 0.03125f;
      }
      __syncthreads();
      float mx = -1e30f;
#pragma unroll 16
      for (int i2 = 0; i2 < 128; ++i2) mx = fmaxf(mx, sarr[i2]);
      if (tid < 128) earr[tid] = expf(sarr[tid] - mx);
      __syncthreads();
      float sum = 0.f;
#pragma unroll 16
      for (int i2 = 0; i2 < 128; ++i2) sum += earr[i2];
      float winv = 1.f / sum;
      f32x4 cacc; cacc[0]=0.f; cacc[1]=0.f; cacc[2]=0.f; cacc[3]=0.f;
      const unsigned short* eb = enc_bf + ((size_t)b << 17) + tid * 4;
#pragma unroll 4
      for (int s2 = 0; s2 < 128; ++s2) {
        float w = earr[s2] * winv;
        uint2 ev = *(const uint2*)(eb + ((size_t)s2 << 10));
        cacc[0] += w * bflo(ev.x); cacc[1] += w * bfhi(ev.x);
        cacc[2] += w * bflo(ev.y); cacc[3] += w * bfhi(ev.y);
      }
      unsigned long long cw = (unsigned long long)pk2(cacc[0], cacc[1])
                            | ((unsigned long long)pk2(cacc[2], cacc[3]) << 32);
      st64_sc1((unsigned long long*)(hcat + ((size_t)t * 32 + b) * 2048 + 1024 + tid * 4), cw);
      __syncthreads();                     // drain ctx stores
      if (tid == 0) stw(&arrC[blk << 2], gen);
    }

    // ---------------- GRU phase (overlapped) ------------------------------
    const int part = wave >> 1;
    const int kh2 = (wave & 1) << 9;
    const unsigned short* abase;
    size_t astr;
    const unsigned short* Wl;
    if (part == 0) {
      if (t && blk >= 32) waitword(relH, t);   // attn blocks already waited
      if (t == 0) { abase = enc_bf + (size_t)127 * 1024; astr = 131072; }
      else { abase = hcat + (size_t)(t - 1) * 32 * 2048; astr = 2048; }
      Wl = Wh;
    } else {
      waitword(relC, gen);                 // ctx(t) published
      abase = hcat + (size_t)t * 32 * 2048 + 1024; astr = 2048;
      Wl = Wx;
    }
    f32x4 acc[2][2];
#pragma unroll
    for (int m = 0; m < 2; ++m)
#pragma unroll
      for (int n = 0; n < 2; ++n) { acc[m][n][0]=0.f; acc[m][n][1]=0.f; acc[m][n][2]=0.f; acc[m][n][3]=0.f; }
#pragma unroll
    for (int hh = 0; hh < 2; ++hh) {
      bf16x8 af[2][8];
#pragma unroll
      for (int kk = 0; kk < 8; ++kk) {
        int k = kh2 + hh * 256 + kk * 32 + ((lane >> 4) << 3);
        af[0][kk] = *(const bf16x8*)(abase + (size_t)(lane & 15) * astr + k);
        af[1][kk] = *(const bf16x8*)(abase + (size_t)(16 + (lane & 15)) * astr + k);
      }
#pragma unroll
      for (int kk = 0; kk < 8; ++kk) {
        int c = ((kh2 + hh * 256 + kk * 32) >> 3) + (lane >> 4);
#pragma unroll
        for (int n = 0; n < 2; ++n) {
          int wr = n * 16 + (lane & 15);
          bf16x8 bfr = *(const bf16x8*)&Wl[(wr << 10) + ((c ^ (wr & 7)) << 3)];
          acc[0][n] = __builtin_amdgcn_mfma_f32_16x16x32_bf16(af[0][kk], bfr, acc[0][n], 0, 0, 0);
          acc[1][n] = __builtin_amdgcn_mfma_f32_16x16x32_bf16(af[1][kk], bfr, acc[1][n], 0, 0, 0);
        }
      }
    }
#pragma unroll
    for (int m = 0; m < 2; ++m)
#pragma unroll
      for (int n = 0; n < 2; ++n)
        *(f32x4*)&Cred[((((wave * 2 + m) * 2 + n) * 64) + lane) << 2] = acc[m][n];
    __syncthreads();

    {
      float Chr = 0.f, Chz = 0.f, Chn = 0.f, Cxr = 0.f, Cxz = 0.f, Cxn = 0.f;
#pragma unroll
      for (int w = 0; w < 2; ++w) {
        Chr += Cred[((((w * 2 + gm) * 2 + 0) * 64 + glb + gj) << 2) + greg];
        Chz += Cred[((((w * 2 + gm) * 2 + 0) * 64 + glb + gj + 8) << 2) + greg];
        Chn += Cred[((((w * 2 + gm) * 2 + 1) * 64 + glb + gj) << 2) + greg];
        Cxr += Cred[(((((w + 2) * 2 + gm) * 2 + 0) * 64 + glb + gj) << 2) + greg];
        Cxz += Cred[(((((w + 2) * 2 + gm) * 2 + 0) * 64 + glb + gj + 8) << 2) + greg];
        Cxn += Cred[(((((w + 2) * 2 + gm) * 2 + 1) * 64 + glb + gj) << 2) + greg];
      }
      float r = sigm(g0 + Cxr + Chr + bh0);
      float z = sigm(g1 + Cxz + Chz + bh1);
      float n2 = tanhf(g2 + Cxn + r * (Chn + bh2));
      float h2 = (1.f - z) * n2 + z * hpv;
      hpv = h2;
      unsigned short sv = f2bf(h2);
      unsigned ov = (unsigned)__shfl_xor((int)(unsigned)sv, 1);
      if ((tid & 1) == 0) {
        unsigned pv = (unsigned)sv | (ov << 16);
        st32_sc1((unsigned*)&hcat[((size_t)t * 32 + gb) * 2048 + j0 + gj], pv);
      }
    }
    __syncthreads();                       // drain h stores
    if (tid == 0) stw(&arrH[blk << 2], gen);
  }
}

// ---------------------------------------------------------------------------
extern "C" void kernel_launch(void* const* d_in, const int* in_sizes, int n_in,
                              void* d_out, int out_size, void* d_ws, size_t ws_size,
                              hipStream_t stream)
{
  const float* features = (const float*)d_in[0];
  const int*   toks     = (const int*)d_in[1];
  const float* temp_W = (const float*)d_in[2];  const float* temp_b = (const float*)d_in[3];
  const float* hum_W  = (const float*)d_in[4];  const float* hum_b  = (const float*)d_in[5];
  const float* cloud_W= (const float*)d_in[6];  const float* cloud_b= (const float*)d_in[7];
  const float* time_W = (const float*)d_in[8];  const float* time_b = (const float*)d_in[9];
  const float* other_W= (const float*)d_in[10]; const float* other_b= (const float*)d_in[11];
  const float* fi_W   = (const float*)d_in[12]; const float* fi_b   = (const float*)d_in[13];
  const float* enc_wih= (const float*)d_in[14]; const float* enc_whh= (const float*)d_in[15];
  const float* enc_bih= (const float*)d_in[16]; const float* enc_bhh= (const float*)d_in[17];
  const float* emb    = (const float*)d_in[18];
  const float* attn_W = (const float*)d_in[19]; const float* attn_b = (const float*)d_in[20];
  const float* dec_wih= (const float*)d_in[21]; const float* dec_whh= (const float*)d_in[22];
  const float* dec_bih= (const float*)d_in[23]; const float* dec_bhh= (const float*)d_in[24];
  const float* out_W  = (const float*)d_in[25]; const float* out_b  = (const float*)d_in[26];
  float* out = (float*)d_out;
  char* ws = (char*)d_ws;

  int*            arrE    = (int*)(ws + 0);                        // 64*16B
  int*            arrH    = (int*)(ws + 1024);                     // 128*16B
  int*            arrC    = (int*)(ws + 3072);                     // 32*16B
  int*            relE    = (int*)(ws + 3584);
  int*            relC    = (int*)(ws + 3600);
  int*            relH    = (int*)(ws + 3616);
  float*          Mf      = (float*)(ws + 4096);                   // 64 KB
  float*          b0v     = (float*)(ws + 69632);                  // 4 KB
  float*          hfp     = (float*)(ws + 73728);                  // 128 KB (fp32 h127)
  unsigned short* hcat    = (unsigned short*)(ws + 466944);        // 8 MB  [2048][2048]
  unsigned short* keys_bf = (unsigned short*)(ws + 8855552);       // 8 MB
  unsigned short* enc_bf  = (unsigned short*)(ws + 17244160);      // 8 MB
  float*          gi_e    = (float*)(ws + 25632768);               // 24 MB
  float*          gi_all  = (float*)(ws + 50798592);               // 48 MB
  unsigned short* proj_bf = (unsigned short*)(ws + 101130240);     // 8 MB
  unsigned short* e_bf    = (unsigned short*)(ws + 109518848);     // 4 MB
  unsigned short* wihE_bf = (unsigned short*)(ws + 113713152);     // 6 MB
  unsigned short* attnW_bf= (unsigned short*)(ws + 120004608);     // 2 MB
  unsigned short* wihD_bf = (unsigned short*)(ws + 122101760);     // 6 MB
  unsigned short* outW_bf = (unsigned short*)(ws + 25632768);      // aliases dead gi_e/gi_all

  // zero barrier flags + hcat padding rows (2016..2047)
  hipMemsetAsync(ws, 0, 4096, stream);
  hipMemsetAsync(ws + 466944 + (size_t)2016 * 2048 * 2, 0, 32 * 2048 * 2, stream);

  // weight conversions
  k_conv<<<1536, 256, 0, stream>>>(enc_wih, wihE_bf, 393216);
  k_conv<<<512, 256, 0, stream>>>(attn_W, attnW_bf, 131072);
  k_conv_str<<<3072, 256, 0, stream>>>(dec_wih, wihD_bf);

  // feature pipeline
  k_fold<<<68, 256, 0, stream>>>(temp_W, temp_b, hum_W, hum_b, cloud_W, cloud_b,
                                 time_W, time_b, other_W, other_b, fi_W, fi_b, Mf, b0v);
  k_proj<<<dim3(4096, 4), 256, 0, stream>>>(features, Mf, b0v, proj_bf);

  // encoder input gates (batched): gi_all[4096,3072]
  gemm_bf<0><<<768, 256, 0, stream>>>(proj_bf, wihE_bf, enc_bih, gi_all, nullptr,
                                      32, 1024, 1024, 1024, 3072, 0);
  // encoder scan (persistent, 64 workers + master)
  k_enc_scan<<<65, 256, 0, stream>>>(gi_all, enc_whh, enc_bhh, hfp, enc_bf, arrE, relE);

  // attention keys (bf16 out)
  gemm_bf<1><<<256, 256, 0, stream>>>(enc_bf, attnW_bf, attn_b, nullptr, keys_bf,
                                      32, 1024, 1024, 1024, 1024, 0);
  // decoder embedding-path gates
  k_gather_e<<<2048, 256, 0, stream>>>(toks, emb, e_bf);
  gemm_bf<0><<<384, 256, 0, stream>>>(e_bf, wihD_bf, dec_bih, gi_e, nullptr,
                                      16, 1024, 1024, 1024, 3072, 0);
  // decoder scan (persistent, 128 workers + master)
  k_dec_scan<<<129, 256, 0, stream>>>(gi_e, dec_whh, dec_wih, dec_bhh, keys_bf,
                                      enc_bf, hcat, hfp, arrC, relC, arrH, relH);

  // batched output projection in two N-halves (outW_bf aliases dead buffers)
  k_conv<<<2048, 256, 0, stream>>>(out_W, outW_bf, 4096000);
  gemm_bf<2><<<2000, 256, 0, stream>>>(hcat, outW_bf, out_b, out, nullptr,
                                       16, 2048, 2048, 2048, 0, 0);
  k_conv<<<2048, 256, 0, stream>>>(out_W + (size_t)16000 * 2048, outW_bf, 4096000);
  gemm_bf<2><<<2000, 256, 0, stream>>>(hcat, outW_bf, out_b + 16000, out, nullptr,
                                       16, 2048, 2048, 2048, 0, 16000);
  // out[:, 0, :] one-hot
  k_onehot<<<4000, 256, 0, stream>>>(toks, out);
}

// Round 6
// 2645.440 us; speedup vs baseline: 1.2779x; 1.1244x over previous
//
#include <hip/hip_runtime.h>

typedef float f32x4 __attribute__((ext_vector_type(4)));
typedef __bf16 bf16x8 __attribute__((ext_vector_type(8)));

#define DI static __device__ __forceinline__

DI unsigned short f2bf(float f) {
  unsigned u = __float_as_uint(f);
  u = (u + 0x7fffu + ((u >> 16) & 1u)) >> 16;
  return (unsigned short)u;
}
DI unsigned pk2(float lo, float hi) {
  return (unsigned)f2bf(lo) | ((unsigned)f2bf(hi) << 16);
}
DI float bflo(unsigned u) { return __uint_as_float(u << 16); }
DI float bfhi(unsigned u) { return __uint_as_float(u & 0xffff0000u); }
DI float sigm(float x) { return 1.0f / (1.0f + expf(-x)); }

DI void gl_lds16(const unsigned short* g, unsigned short* l) {
  __builtin_amdgcn_global_load_lds(
      (const __attribute__((address_space(1))) unsigned int*)g,
      (__attribute__((address_space(3))) unsigned int*)l, 16, 0, 0);
}

DI void st32_sc1(unsigned* p, unsigned v) {
  __hip_atomic_store(p, v, __ATOMIC_RELAXED, __HIP_MEMORY_SCOPE_AGENT);
}
DI void st64_sc1(unsigned long long* p, unsigned long long v) {
  __hip_atomic_store(p, v, __ATOMIC_RELAXED, __HIP_MEMORY_SCOPE_AGENT);
}
DI int ldw(const int* p) {
  return __hip_atomic_load(p, __ATOMIC_RELAXED, __HIP_MEMORY_SCOPE_AGENT);
}
DI void stw(int* p, int v) {
  __hip_atomic_store(p, v, __ATOMIC_RELAXED, __HIP_MEMORY_SCOPE_AGENT);
}

// Wait on a replicated release word: ONE load per wave (lane 0), broadcast.
DI void waitrel(const int* relbase, int repl, int target) {
  const int* w = relbase + repl * 32;    // 128B-spaced replicas
  for (;;) {
    int v = 0;
    if ((threadIdx.x & 63) == 0) v = ldw(w);
    v = __shfl(v, 0);
    if (v >= target) break;
    __builtin_amdgcn_s_sleep(2);
  }
  asm volatile("" ::: "memory");
}
// Master: store release value to all 8 replicas (call with >=8 lanes active).
DI void strel(int* relbase, int v) {
  int l = threadIdx.x & 63;
  if (l < 8) stw(relbase + l * 32, v);
}

// ---------------------------------------------------------------------------
// Fold tiny per-feature projections + fi into M[1024][16], b0[1024]
// ---------------------------------------------------------------------------
__global__ void k_fold(const float* __restrict__ tW, const float* __restrict__ tb,
                       const float* __restrict__ hW, const float* __restrict__ hb,
                       const float* __restrict__ cW, const float* __restrict__ cb,
                       const float* __restrict__ tiW, const float* __restrict__ tib,
                       const float* __restrict__ oW, const float* __restrict__ ob,
                       const float* __restrict__ fiW, const float* __restrict__ fib,
                       float* __restrict__ M, float* __restrict__ b0v)
{
  int g = blockIdx.x * 256 + threadIdx.x;
  if (g >= 1024 * 17) return;
  int h = g / 17, f = g - h * 17;
  const float* fw = fiW + (size_t)h * 2048;
  float s = 0.f;
  if (f == 16) {
    for (int k = 0; k < 256; ++k) s += fw[k] * tb[k];
    for (int k = 0; k < 256; ++k) s += fw[256 + k] * hb[k];
    for (int k = 0; k < 256; ++k) s += fw[512 + k] * cb[k];
    for (int k = 0; k < 256; ++k) s += fw[768 + k] * tib[k];
    for (int r = 0; r < 1024; ++r) s += fw[1024 + r] * ob[r];
    b0v[h] = s + fib[h];
  } else if (f == 0) {
    for (int k = 0; k < 256; ++k) s += fw[k] * tW[k];
    M[h * 16 + 0] = s;
  } else if (f == 1) {
    for (int k = 0; k < 256; ++k) s += fw[256 + k] * hW[k];
    M[h * 16 + 1] = s;
  } else if (f == 2) {
    for (int k = 0; k < 256; ++k) s += fw[512 + k] * cW[k];
    M[h * 16 + 2] = s;
  } else if (f == 11) {
    for (int k = 0; k < 256; ++k) s += fw[768 + k] * tiW[2 * k];
    M[h * 16 + 11] = s;
  } else if (f == 12) {
    for (int k = 0; k < 256; ++k) s += fw[768 + k] * tiW[2 * k + 1];
    M[h * 16 + 12] = s;
  } else {
    int col = (f <= 10) ? (f - 3) : (f - 5);
    for (int r = 0; r < 1024; ++r) s += fw[1024 + r] * oW[r * 11 + col];
    M[h * 16 + f] = s;
  }
}

__global__ __launch_bounds__(256)
void k_proj(const float* __restrict__ feat, const float* __restrict__ M,
            const float* __restrict__ b0v, unsigned short* __restrict__ proj)
{
  __shared__ float ft[16];
  int bs = blockIdx.x;
  int h = blockIdx.y * 256 + threadIdx.x;
  if (threadIdx.x < 16) ft[threadIdx.x] = feat[bs * 16 + threadIdx.x];
  __syncthreads();
  float sum = b0v[h];
  const float* mr = M + h * 16;
#pragma unroll
  for (int f = 0; f < 16; ++f) sum += mr[f] * ft[f];
  proj[(size_t)bs * 1024 + h] = f2bf(tanhf(sum));
}

// ---------------------------------------------------------------------------
// fp32 -> bf16 converters
// ---------------------------------------------------------------------------
__global__ void k_conv(const float* __restrict__ s, unsigned short* __restrict__ d, int n8)
{
  for (long i = (long)blockIdx.x * 256 + threadIdx.x; i < n8; i += (long)gridDim.x * 256) {
    const float* p = s + i * 8;
    f32x4 a = *(const f32x4*)p, b = *(const f32x4*)(p + 4);
    uint4 o;
    o.x = pk2(a[0], a[1]); o.y = pk2(a[2], a[3]);
    o.z = pk2(b[0], b[1]); o.w = pk2(b[2], b[3]);
    *(uint4*)(d + i * 8) = o;
  }
}

__global__ void k_conv_str(const float* __restrict__ s, unsigned short* __restrict__ d)
{
  int r = blockIdx.x;
  int c = threadIdx.x * 4;
  f32x4 a = *(const f32x4*)(s + (size_t)r * 2048 + c);
  uint2 o; o.x = pk2(a[0], a[1]); o.y = pk2(a[2], a[3]);
  *(uint2*)(d + (size_t)r * 1024 + c) = o;
}

__global__ void k_gather_e(const int* __restrict__ toks, const float* __restrict__ emb,
                           unsigned short* __restrict__ e_bf)
{
  int row = blockIdx.x;               // 2048
  int t = row >> 5, b = row & 31;
  unsigned short* dst = e_bf + (size_t)row * 1024 + threadIdx.x * 4;
  if (t < 63) {
    int tok = toks[b * 64 + t];
    f32x4 a = *(const f32x4*)(emb + (size_t)tok * 1024 + threadIdx.x * 4);
    uint2 o; o.x = pk2(a[0], a[1]); o.y = pk2(a[2], a[3]);
    *(uint2*)dst = o;
  } else {
    uint2 o; o.x = 0u; o.y = 0u;
    *(uint2*)dst = o;
  }
}

__global__ void k_onehot(const int* __restrict__ toks, float* __restrict__ out)
{
  int i = blockIdx.x * 256 + threadIdx.x;
  if (i >= 32 * 32000) return;
  int b = i / 32000, v = i - b * 32000;
  out[(size_t)b * 64 * 32000 + v] = (v == toks[0]) ? 1.0f : 0.0f;
}

// ---------------------------------------------------------------------------
// bf16 MFMA GEMM, m97 structure: C[M,N] = A[M,K] * B[N,K]^T + bias[N]
// ---------------------------------------------------------------------------
template<int MODE>
__global__ __launch_bounds__(256)
void gemm_bf(const unsigned short* __restrict__ A, const unsigned short* __restrict__ B,
             const float* __restrict__ bias, float* __restrict__ Cf,
             unsigned short* __restrict__ Cb,
             int tiles_m, int K, int lda, int ldb, int ldc, int coloff)
{
  __shared__ unsigned short As[4096];
  __shared__ unsigned short Bs[4096];
  const int nblk = gridDim.x;
  const int cpx = nblk >> 3;
  const int bid = blockIdx.x;
  const int id = (bid & 7) * cpx + (bid >> 3);     // XCD-contiguous work ids
  const int tm = id % tiles_m, tn = id / tiles_m;
  const int tid = threadIdx.x;
  const int lane = tid & 63, wave = tid >> 6;
  const int wm = (wave & 1) << 6, wn = (wave >> 1) << 6;
  const int r0 = tid >> 2, kc0 = (tid & 3) << 3;
  const unsigned short* ga0 = A + (size_t)(tm * 128 + r0) * lda + kc0;
  const unsigned short* ga1 = A + (size_t)(tm * 128 + 64 + r0) * lda + kc0;
  const unsigned short* gb0 = B + (size_t)(tn * 128 + r0) * ldb + kc0;
  const unsigned short* gb1 = B + (size_t)(tn * 128 + 64 + r0) * ldb + kc0;
  const int lr = lane & 15, lkb = (lane >> 4) << 3;

  f32x4 acc[4][4];
#pragma unroll
  for (int m = 0; m < 4; ++m)
#pragma unroll
    for (int n = 0; n < 4; ++n) { acc[m][n][0]=0.f; acc[m][n][1]=0.f; acc[m][n][2]=0.f; acc[m][n][3]=0.f; }

  for (int kt = 0; kt < K; kt += 32) {
    __syncthreads();
    gl_lds16(ga0 + kt, &As[tid * 8]);
    gl_lds16(ga1 + kt, &As[(tid + 256) * 8]);
    gl_lds16(gb0 + kt, &Bs[tid * 8]);
    gl_lds16(gb1 + kt, &Bs[(tid + 256) * 8]);
    __syncthreads();
    bf16x8 af[4], bfv[4];
#pragma unroll
    for (int m = 0; m < 4; ++m) af[m] = *(const bf16x8*)&As[(wm + m * 16 + lr) * 32 + lkb];
#pragma unroll
    for (int n = 0; n < 4; ++n) bfv[n] = *(const bf16x8*)&Bs[(wn + n * 16 + lr) * 32 + lkb];
#pragma unroll
    for (int m = 0; m < 4; ++m)
#pragma unroll
      for (int n = 0; n < 4; ++n)
        acc[m][n] = __builtin_amdgcn_mfma_f32_16x16x32_bf16(af[m], bfv[n], acc[m][n], 0, 0, 0);
  }

#pragma unroll
  for (int m = 0; m < 4; ++m) {
    int rb = tm * 128 + wm + m * 16 + ((lane >> 4) << 2);
#pragma unroll
    for (int n = 0; n < 4; ++n) {
      int c = tn * 128 + wn + n * 16 + lr;
      float bb = bias[c];
#pragma unroll
      for (int i = 0; i < 4; ++i) {
        float v = acc[m][n][i] + bb;
        int r = rb + i;
        if (MODE == 0) {
          Cf[(size_t)r * ldc + c] = v;
        } else if (MODE == 1) {
          Cb[(size_t)r * ldc + c] = f2bf(v);
        } else {
          if (r < 2016) {
            int t = r >> 5, b2 = r & 31;
            Cf[((size_t)b2 * 64 + t + 1) * 32000 + coloff + c] = v;
          }
        }
      }
    }
  }
}

// ---------------------------------------------------------------------------
// Persistent encoder scan. 64 worker blocks + 1 master block.
// h history lives in enc_bf[b][s][j] (single-assignment): sc1-publish,
// normal-load. h(-1)=0 -> skip MFMA at s=0.
// ---------------------------------------------------------------------------
__global__ __launch_bounds__(256, 1)
void k_enc_scan(const float* __restrict__ gi_all, const float* __restrict__ whh,
                const float* __restrict__ bhh, float* __restrict__ hfp,
                unsigned short* __restrict__ enc_bf,
                int* __restrict__ arrE, int* __restrict__ relE)
{
  const int tid = threadIdx.x;
  const int blk = blockIdx.x;
  if (blk == 64) {                         // master: sweep arrivals, fan-out release
    if (tid < 64) {
      for (int g = 1; g <= 128; ++g) {
        for (;;) {
          int v = ldw(&arrE[tid << 4]);
          if (__all(v >= g)) break;
          __builtin_amdgcn_s_sleep(1);
        }
        asm volatile("" ::: "memory");
        strel(relE, g);
      }
    }
    return;
  }

  __shared__ unsigned short W[48 * 1024];
  __shared__ float Cred[4 * 2 * 3 * 64 * 4];
  const int lane = tid & 63, wave = tid >> 6;
  const int j0 = blk * 16;
  const int repl = blk & 7;

  for (int i = tid; i < 48 * 128; i += 256) {
    int r = i >> 7, c = i & 127;
    int gr = ((r >> 4) << 10) + j0 + (r & 15);
    const float* src = whh + ((size_t)gr << 10) + (c << 3);
    f32x4 a = *(const f32x4*)src, b = *(const f32x4*)(src + 4);
    uint4 o;
    o.x = pk2(a[0], a[1]); o.y = pk2(a[2], a[3]);
    o.z = pk2(b[0], b[1]); o.w = pk2(b[2], b[3]);
    *(uint4*)&W[(r << 10) + ((c ^ (r & 7)) << 3)] = o;
  }
  __syncthreads();

  int cb[2], cj[2], clb[2], creg[2], cm[2];
  float bh0[2], bh1[2], bh2[2];
  float hp[2] = {0.f, 0.f};
#pragma unroll
  for (int cc = 0; cc < 2; ++cc) {
    int cell = tid + (cc << 8);
    cb[cc] = cell >> 4; cj[cc] = cell & 15;
    clb[cc] = ((cb[cc] & 15) >> 2) * 16;
    creg[cc] = cb[cc] & 3; cm[cc] = cb[cc] >> 4;
    bh0[cc] = bhh[j0 + cj[cc]];
    bh1[cc] = bhh[1024 + j0 + cj[cc]];
    bh2[cc] = bhh[2048 + j0 + cj[cc]];
  }

#pragma unroll 1
  for (int s = 0; s < 128; ++s) {
    float gp[2][3];
#pragma unroll
    for (int cc = 0; cc < 2; ++cc) {
      const float* gi = gi_all + ((size_t)cb[cc] * 128 + s) * 3072 + j0 + cj[cc];
      gp[cc][0] = gi[0]; gp[cc][1] = gi[1024]; gp[cc][2] = gi[2048];
    }

    f32x4 acc[2][3];
#pragma unroll
    for (int m = 0; m < 2; ++m)
#pragma unroll
      for (int n = 0; n < 3; ++n) { acc[m][n][0]=0.f; acc[m][n][1]=0.f; acc[m][n][2]=0.f; acc[m][n][3]=0.f; }

    if (s > 0) {
      waitrel(relE, repl, s);              // h(s-1) published
      const unsigned short* hr = enc_bf + (size_t)(s - 1) * 1024;   // + b*131072
      const int k0 = wave << 8;
      bf16x8 af[2][8];
#pragma unroll
      for (int kk = 0; kk < 8; ++kk) {
        int k = k0 + kk * 32 + ((lane >> 4) << 3);
        af[0][kk] = *(const bf16x8*)(hr + (size_t)(lane & 15) * 131072 + k);
        af[1][kk] = *(const bf16x8*)(hr + (size_t)(16 + (lane & 15)) * 131072 + k);
      }
#pragma unroll
      for (int kk = 0; kk < 8; ++kk) {
        int c = ((k0 + kk * 32) >> 3) + (lane >> 4);
#pragma unroll
        for (int n = 0; n < 3; ++n) {
          int wr = n * 16 + (lane & 15);
          bf16x8 bfr = *(const bf16x8*)&W[(wr << 10) + ((c ^ (wr & 7)) << 3)];
          acc[0][n] = __builtin_amdgcn_mfma_f32_16x16x32_bf16(af[0][kk], bfr, acc[0][n], 0, 0, 0);
          acc[1][n] = __builtin_amdgcn_mfma_f32_16x16x32_bf16(af[1][kk], bfr, acc[1][n], 0, 0, 0);
        }
      }
    }
#pragma unroll
    for (int m = 0; m < 2; ++m)
#pragma unroll
      for (int n = 0; n < 3; ++n)
        *(f32x4*)&Cred[((((wave * 2 + m) * 3 + n) * 64) + lane) << 2] = acc[m][n];
    __syncthreads();

    float h2v[2];
#pragma unroll
    for (int cc = 0; cc < 2; ++cc) {
      int lj = clb[cc] + cj[cc], reg = creg[cc], m = cm[cc];
      float Cr = 0.f, Cz = 0.f, Cn = 0.f;
#pragma unroll
      for (int w = 0; w < 4; ++w) {
        Cr += Cred[((((w * 2 + m) * 3 + 0) * 64 + lj) << 2) + reg];
        Cz += Cred[((((w * 2 + m) * 3 + 1) * 64 + lj) << 2) + reg];
        Cn += Cred[((((w * 2 + m) * 3 + 2) * 64 + lj) << 2) + reg];
      }
      float r = sigm(gp[cc][0] + Cr + bh0[cc]);
      float z = sigm(gp[cc][1] + Cz + bh1[cc]);
      float n = tanhf(gp[cc][2] + r * (Cn + bh2[cc]));
      float h2 = (1.f - z) * n + z * hp[cc];
      h2v[cc] = h2; hp[cc] = h2;
    }
    if (s == 127) {
      hfp[cb[0] * 1024 + j0 + cj[0]] = h2v[0];
      hfp[cb[1] * 1024 + j0 + cj[1]] = h2v[1];
    }
    unsigned short s0 = f2bf(h2v[0]), s1 = f2bf(h2v[1]);
    unsigned o0 = (unsigned)__shfl_xor((int)(unsigned)s0, 1);
    unsigned o1 = (unsigned)__shfl_xor((int)(unsigned)s1, 1);
    if ((tid & 1) == 0) {
      int j = cj[0];                       // even
      st32_sc1((unsigned*)&enc_bf[((size_t)cb[0] * 128 + s) * 1024 + j0 + j],
               (unsigned)s0 | (o0 << 16));
      st32_sc1((unsigned*)&enc_bf[((size_t)cb[1] * 128 + s) * 1024 + j0 + j],
               (unsigned)s1 | (o1 << 16));
    }
    __syncthreads();                       // drain stores before arrival
    if (tid == 0) stw(&arrE[blk << 4], s + 1);
  }
}

// ---------------------------------------------------------------------------
// Persistent decoder scan. 32 attn blocks + 128 GRU blocks + 1 master (161).
// Monotonic release word relD: 2t+1 = ctx(t) ready, 2t+2 = h(t) ready.
// ---------------------------------------------------------------------------
__global__ __launch_bounds__(256, 1)
void k_dec_scan(const float* __restrict__ gi_e, const float* __restrict__ whh,
                const float* __restrict__ wih, const float* __restrict__ bhh,
                const unsigned short* __restrict__ keys,
                const unsigned short* __restrict__ enc_bf,
                unsigned short* __restrict__ hcat, const float* __restrict__ hfp0,
                int* __restrict__ arrC, int* __restrict__ arrH,
                int* __restrict__ relD)
{
  const int tid = threadIdx.x;
  const int blk = blockIdx.x;
  const int repl = blk & 7;

  if (blk == 160) {                        // master
    if (tid < 64) {
      for (int t = 0; t < 63; ++t) {
        for (;;) {
          int v = (tid < 32) ? ldw(&arrC[tid << 4]) : 0x7fffffff;
          if (__all(v >= t + 1)) break;
          __builtin_amdgcn_s_sleep(1);
        }
        asm volatile("" ::: "memory");
        strel(relD, 2 * t + 1);
        for (;;) {
          int v0 = ldw(&arrH[(tid * 2) << 4]);
          int v1 = ldw(&arrH[(tid * 2 + 1) << 4]);
          if (__all(v0 >= t + 1 && v1 >= t + 1)) break;
          __builtin_amdgcn_s_sleep(1);
        }
        asm volatile("" ::: "memory");
        strel(relD, 2 * t + 2);
      }
    }
    return;
  }

  if (blk < 32) {
    // ------------------------- attention blocks ---------------------------
    __shared__ unsigned short hsh[1024];
    __shared__ float sarr[128];
    __shared__ float earr[128];
    const int b = blk;
#pragma unroll 1
    for (int t = 0; t < 63; ++t) {
      if (t) waitrel(relD, repl, 2 * t);   // h(t-1) published
      const unsigned short* hsrc = (t == 0)
          ? (enc_bf + (size_t)b * 131072 + (size_t)127 * 1024)
          : (hcat + ((size_t)(t - 1) * 32 + b) * 2048);
      *(uint2*)&hsh[tid * 4] = *(const uint2*)(hsrc + tid * 4);
      __syncthreads();
      {
        int sp = tid >> 1, kh = (tid & 1) << 9;
        const unsigned short* kr = keys + ((size_t)b * 128 + sp) * 1024 + kh;
        float a0 = 0.f, a1 = 0.f, a2 = 0.f, a3 = 0.f;
#pragma unroll 8
        for (int c = 0; c < 512; c += 8) {
          uint4 kv = *(const uint4*)(kr + c);
          uint4 hv = *(const uint4*)&hsh[kh + c];
          a0 += bflo(kv.x) * bflo(hv.x) + bfhi(kv.x) * bfhi(hv.x);
          a1 += bflo(kv.y) * bflo(hv.y) + bfhi(kv.y) * bfhi(hv.y);
          a2 += bflo(kv.z) * bflo(hv.z) + bfhi(kv.z) * bfhi(hv.z);
          a3 += bflo(kv.w) * bflo(hv.w) + bfhi(kv.w) * bfhi(hv.w);
        }
        float a = (a0 + a1) + (a2 + a3);
        a += __shfl_xor(a, 1);
        if ((tid & 1) == 0) sarr[sp] = a * 0.03125f;
      }
      __syncthreads();
      float m0 = -1e30f, m1 = -1e30f, m2 = -1e30f, m3 = -1e30f;
#pragma unroll 8
      for (int i2 = 0; i2 < 128; i2 += 4) {
        m0 = fmaxf(m0, sarr[i2]); m1 = fmaxf(m1, sarr[i2 + 1]);
        m2 = fmaxf(m2, sarr[i2 + 2]); m3 = fmaxf(m3, sarr[i2 + 3]);
      }
      float mx = fmaxf(fmaxf(m0, m1), fmaxf(m2, m3));
      if (tid < 128) earr[tid] = expf(sarr[tid] - mx);
      __syncthreads();
      float s0 = 0.f, s1 = 0.f, s2 = 0.f, s3 = 0.f;
#pragma unroll 8
      for (int i2 = 0; i2 < 128; i2 += 4) {
        s0 += earr[i2]; s1 += earr[i2 + 1]; s2 += earr[i2 + 2]; s3 += earr[i2 + 3];
      }
      float winv = 1.f / ((s0 + s1) + (s2 + s3));
      f32x4 cacc; cacc[0]=0.f; cacc[1]=0.f; cacc[2]=0.f; cacc[3]=0.f;
      const unsigned short* eb = enc_bf + ((size_t)b << 17) + tid * 4;
#pragma unroll 4
      for (int s2i = 0; s2i < 128; ++s2i) {
        float w = earr[s2i] * winv;
        uint2 ev = *(const uint2*)(eb + ((size_t)s2i << 10));
        cacc[0] += w * bflo(ev.x); cacc[1] += w * bfhi(ev.x);
        cacc[2] += w * bflo(ev.y); cacc[3] += w * bfhi(ev.y);
      }
      unsigned long long cw = (unsigned long long)pk2(cacc[0], cacc[1])
                            | ((unsigned long long)pk2(cacc[2], cacc[3]) << 32);
      st64_sc1((unsigned long long*)(hcat + ((size_t)t * 32 + b) * 2048 + 1024 + tid * 4), cw);
      __syncthreads();                     // drain ctx stores
      if (tid == 0) stw(&arrC[blk << 4], t + 1);
    }
    return;
  }

  // --------------------------- GRU blocks ---------------------------------
  __shared__ unsigned short Wh[32 * 1024];
  __shared__ unsigned short Wx[32 * 1024];
  __shared__ float Cred[4 * 2 * 2 * 64 * 4];
  const int lane = tid & 63, wave = tid >> 6;
  const int gblk = blk - 32;               // 0..127
  const int j0 = gblk * 8;

  for (int i = tid; i < 32 * 128; i += 256) {
    int r = i >> 7, c = i & 127;
    int off = (r << 10) + ((c ^ (r & 7)) << 3);
    uint4 oh, ox;
    oh.x = oh.y = oh.z = oh.w = 0u; ox = oh;
    if (r < 24) {
      int gr = ((r >> 3) << 10) + j0 + (r & 7);
      const float* sh = whh + ((size_t)gr << 10) + (c << 3);
      f32x4 a = *(const f32x4*)sh, b = *(const f32x4*)(sh + 4);
      oh.x = pk2(a[0], a[1]); oh.y = pk2(a[2], a[3]);
      oh.z = pk2(b[0], b[1]); oh.w = pk2(b[2], b[3]);
      const float* sx = wih + ((size_t)gr << 11) + 1024 + (c << 3);
      f32x4 e = *(const f32x4*)sx, f = *(const f32x4*)(sx + 4);
      ox.x = pk2(e[0], e[1]); ox.y = pk2(e[2], e[3]);
      ox.z = pk2(f[0], f[1]); ox.w = pk2(f[2], f[3]);
    }
    *(uint4*)&Wh[off] = oh;
    *(uint4*)&Wx[off] = ox;
  }
  __syncthreads();

  const int gb = tid >> 3, gj = tid & 7;
  const int glb = ((gb & 15) >> 2) * 16;
  const int greg = gb & 3, gm = gb >> 4;
  const float bh0 = bhh[j0 + gj];
  const float bh1 = bhh[1024 + j0 + gj];
  const float bh2 = bhh[2048 + j0 + gj];
  float hpv = hfp0[gb * 1024 + j0 + gj];

#pragma unroll 1
  for (int t = 0; t < 63; ++t) {
    const float* gie = gi_e + ((size_t)t * 32 + gb) * 3072 + j0 + gj;
    float g0 = gie[0], g1 = gie[1024], g2 = gie[2048];

    const int part = wave >> 1;
    const int kh2 = (wave & 1) << 9;
    const unsigned short* abase;
    size_t astr;
    const unsigned short* Wl;
    if (part == 0) {
      if (t) waitrel(relD, repl, 2 * t);   // h(t-1) published
      if (t == 0) { abase = enc_bf + (size_t)127 * 1024; astr = 131072; }
      else { abase = hcat + (size_t)(t - 1) * 32 * 2048; astr = 2048; }
      Wl = Wh;
    } else {
      waitrel(relD, repl, 2 * t + 1);      // ctx(t) published
      abase = hcat + (size_t)t * 32 * 2048 + 1024; astr = 2048;
      Wl = Wx;
    }
    f32x4 acc[2][2];
#pragma unroll
    for (int m = 0; m < 2; ++m)
#pragma unroll
      for (int n = 0; n < 2; ++n) { acc[m][n][0]=0.f; acc[m][n][1]=0.f; acc[m][n][2]=0.f; acc[m][n][3]=0.f; }
#pragma unroll
    for (int hh = 0; hh < 2; ++hh) {
      bf16x8 af[2][8];
#pragma unroll
      for (int kk = 0; kk < 8; ++kk) {
        int k = kh2 + hh * 256 + kk * 32 + ((lane >> 4) << 3);
        af[0][kk] = *(const bf16x8*)(abase + (size_t)(lane & 15) * astr + k);
        af[1][kk] = *(const bf16x8*)(abase + (size_t)(16 + (lane & 15)) * astr + k);
      }
#pragma unroll
      for (int kk = 0; kk < 8; ++kk) {
        int c = ((kh2 + hh * 256 + kk * 32) >> 3) + (lane >> 4);
#pragma unroll
        for (int n = 0; n < 2; ++n) {
          int wr = n * 16 + (lane & 15);
          bf16x8 bfr = *(const bf16x8*)&Wl[(wr << 10) + ((c ^ (wr & 7)) << 3)];
          acc[0][n] = __builtin_amdgcn_mfma_f32_16x16x32_bf16(af[0][kk], bfr, acc[0][n], 0, 0, 0);
          acc[1][n] = __builtin_amdgcn_mfma_f32_16x16x32_bf16(af[1][kk], bfr, acc[1][n], 0, 0, 0);
        }
      }
    }
#pragma unroll
    for (int m = 0; m < 2; ++m)
#pragma unroll
      for (int n = 0; n < 2; ++n)
        *(f32x4*)&Cred[((((wave * 2 + m) * 2 + n) * 64) + lane) << 2] = acc[m][n];
    __syncthreads();

    {
      float Chr = 0.f, Chz = 0.f, Chn = 0.f, Cxr = 0.f, Cxz = 0.f, Cxn = 0.f;
#pragma unroll
      for (int w = 0; w < 2; ++w) {
        Chr += Cred[((((w * 2 + gm) * 2 + 0) * 64 + glb + gj) << 2) + greg];
        Chz += Cred[((((w * 2 + gm) * 2 + 0) * 64 + glb + gj + 8) << 2) + greg];
        Chn += Cred[((((w * 2 + gm) * 2 + 1) * 64 + glb + gj) << 2) + greg];
        Cxr += Cred[(((((w + 2) * 2 + gm) * 2 + 0) * 64 + glb + gj) << 2) + greg];
        Cxz += Cred[(((((w + 2) * 2 + gm) * 2 + 0) * 64 + glb + gj + 8) << 2) + greg];
        Cxn += Cred[(((((w + 2) * 2 + gm) * 2 + 1) * 64 + glb + gj) << 2) + greg];
      }
      float r = sigm(g0 + Cxr + Chr + bh0);
      float z = sigm(g1 + Cxz + Chz + bh1);
      float n2 = tanhf(g2 + Cxn + r * (Chn + bh2));
      float h2 = (1.f - z) * n2 + z * hpv;
      hpv = h2;
      unsigned short sv = f2bf(h2);
      unsigned ov = (unsigned)__shfl_xor((int)(unsigned)sv, 1);
      if ((tid & 1) == 0) {
        unsigned pv = (unsigned)sv | (ov << 16);
        st32_sc1((unsigned*)&hcat[((size_t)t * 32 + gb) * 2048 + j0 + gj], pv);
      }
    }
    __syncthreads();                       // drain h stores
    if (tid == 0) stw(&arrH[gblk << 4], t + 1);
  }
}

// ---------------------------------------------------------------------------
extern "C" void kernel_launch(void* const* d_in, const int* in_sizes, int n_in,
                              void* d_out, int out_size, void* d_ws, size_t ws_size,
                              hipStream_t stream)
{
  const float* features = (const float*)d_in[0];
  const int*   toks     = (const int*)d_in[1];
  const float* temp_W = (const float*)d_in[2];  const float* temp_b = (const float*)d_in[3];
  const float* hum_W  = (const float*)d_in[4];  const float* hum_b  = (const float*)d_in[5];
  const float* cloud_W= (const float*)d_in[6];  const float* cloud_b= (const float*)d_in[7];
  const float* time_W = (const float*)d_in[8];  const float* time_b = (const float*)d_in[9];
  const float* other_W= (const float*)d_in[10]; const float* other_b= (const float*)d_in[11];
  const float* fi_W   = (const float*)d_in[12]; const float* fi_b   = (const float*)d_in[13];
  const float* enc_wih= (const float*)d_in[14]; const float* enc_whh= (const float*)d_in[15];
  const float* enc_bih= (const float*)d_in[16]; const float* enc_bhh= (const float*)d_in[17];
  const float* emb    = (const float*)d_in[18];
  const float* attn_W = (const float*)d_in[19]; const float* attn_b = (const float*)d_in[20];
  const float* dec_wih= (const float*)d_in[21]; const float* dec_whh= (const float*)d_in[22];
  const float* dec_bih= (const float*)d_in[23]; const float* dec_bhh= (const float*)d_in[24];
  const float* out_W  = (const float*)d_in[25]; const float* out_b  = (const float*)d_in[26];
  float* out = (float*)d_out;
  char* ws = (char*)d_ws;

  // flags region (16 KB): 64B-padded arrivals, 128B-spaced release replicas
  int*            arrE    = (int*)(ws + 0);                        // 64 x 64B
  int*            arrH    = (int*)(ws + 4096);                     // 128 x 64B
  int*            arrC    = (int*)(ws + 12288);                    // 32 x 64B
  int*            relE    = (int*)(ws + 14336);                    // 8 x 128B
  int*            relD    = (int*)(ws + 15360);                    // 8 x 128B
  float*          Mf      = (float*)(ws + 16384);                  // 64 KB
  float*          b0v     = (float*)(ws + 81920);                  // 4 KB
  float*          hfp     = (float*)(ws + 86016);                  // 128 KB
  unsigned short* hcat    = (unsigned short*)(ws + 217088);        // 8 MB [2048][2048]
  unsigned short* keys_bf = (unsigned short*)(ws + 8605696);       // 8 MB
  unsigned short* enc_bf  = (unsigned short*)(ws + 16994304);      // 8 MB
  float*          gi_e    = (float*)(ws + 25382912);               // 24 MB
  float*          gi_all  = (float*)(ws + 50548736);               // 48 MB
  unsigned short* proj_bf = (unsigned short*)(ws + 100880384);     // 8 MB
  unsigned short* e_bf    = (unsigned short*)(ws + 109268992);     // 4 MB
  unsigned short* wihE_bf = (unsigned short*)(ws + 113463296);     // 6 MB
  unsigned short* attnW_bf= (unsigned short*)(ws + 119754752);     // 2 MB
  unsigned short* wihD_bf = (unsigned short*)(ws + 121851904);     // 6 MB
  unsigned short* outW_bf = (unsigned short*)(ws + 25382912);      // aliases dead gi_e/gi_all

  // zero flags + hcat padding rows (2016..2047)
  hipMemsetAsync(ws, 0, 16384, stream);
  hipMemsetAsync(ws + 217088 + (size_t)2016 * 2048 * 2, 0, 32 * 2048 * 2, stream);

  // weight conversions
  k_conv<<<1536, 256, 0, stream>>>(enc_wih, wihE_bf, 393216);
  k_conv<<<512, 256, 0, stream>>>(attn_W, attnW_bf, 131072);
  k_conv_str<<<3072, 256, 0, stream>>>(dec_wih, wihD_bf);

  // feature pipeline
  k_fold<<<68, 256, 0, stream>>>(temp_W, temp_b, hum_W, hum_b, cloud_W, cloud_b,
                                 time_W, time_b, other_W, other_b, fi_W, fi_b, Mf, b0v);
  k_proj<<<dim3(4096, 4), 256, 0, stream>>>(features, Mf, b0v, proj_bf);

  // encoder input gates (batched): gi_all[4096,3072]
  gemm_bf<0><<<768, 256, 0, stream>>>(proj_bf, wihE_bf, enc_bih, gi_all, nullptr,
                                      32, 1024, 1024, 1024, 3072, 0);
  // encoder scan (persistent, 64 workers + master)
  k_enc_scan<<<65, 256, 0, stream>>>(gi_all, enc_whh, enc_bhh, hfp, enc_bf, arrE, relE);

  // attention keys (bf16 out)
  gemm_bf<1><<<256, 256, 0, stream>>>(enc_bf, attnW_bf, attn_b, nullptr, keys_bf,
                                      32, 1024, 1024, 1024, 1024, 0);
  // decoder embedding-path gates
  k_gather_e<<<2048, 256, 0, stream>>>(toks, emb, e_bf);
  gemm_bf<0><<<384, 256, 0, stream>>>(e_bf, wihD_bf, dec_bih, gi_e, nullptr,
                                      16, 1024, 1024, 1024, 3072, 0);
  // decoder scan (persistent: 32 attn + 128 GRU + 1 master)
  k_dec_scan<<<161, 256, 0, stream>>>(gi_e, dec_whh, dec_wih, dec_bhh, keys_bf,
                                      enc_bf, hcat, hfp, arrC, arrH, relD);

  // batched output projection in two N-halves (outW_bf aliases dead buffers)
  k_conv<<<2048, 256, 0, stream>>>(out_W, outW_bf, 4096000);
  gemm_bf<2><<<2000, 256, 0, stream>>>(hcat, outW_bf, out_b, out, nullptr,
                                       16, 2048, 2048, 2048, 0, 0);
  k_conv<<<2048, 256, 0, stream>>>(out_W + (size_t)16000 * 2048, outW_bf, 4096000);
  gemm_bf<2><<<2000, 256, 0, stream>>>(hcat, outW_bf, out_b + 16000, out, nullptr,
                                       16, 2048, 2048, 2048, 0, 16000);
  // out[:, 0, :] one-hot
  k_onehot<<<4000, 256, 0, stream>>>(toks, out);
}